// Round 5
// baseline (189.242 us; speedup 1.0000x reference)
//
#include <hip/hip_runtime.h>

using bf16x8 = __attribute__((ext_vector_type(8))) short;
using f32x4  = __attribute__((ext_vector_type(4))) float;

// ---- bf16 helpers (RNE) ----------------------------------------------------
__device__ __forceinline__ short f2bf(float x) {
    union { float f; unsigned u; } v; v.f = x;
    unsigned r = v.u + 0x7fffu + ((v.u >> 16) & 1u);
    return (short)(r >> 16);
}
__device__ __forceinline__ float bf2f(short h) {
    union { unsigned u; float f; } v; v.u = ((unsigned)(unsigned short)h) << 16;
    return v.f;
}

// ---------------------------------------------------------------------------
// Pack Wself/Wneigh (fp32, [DIN][256] each) into MFMA B-fragment order,
// split hi/lo bf16.  Ktot = 2*DIN (self rows then neigh rows).
// blk = ks*16+nt:  Wp[blk*1024 + l*8]=hi frag,  Wp[blk*1024 + 512 + l*8]=lo.
// B-frag: lane l holds B[k = ks*32 + (l>>4)*8 + e][n = nt*16 + (l&15)]
// ---------------------------------------------------------------------------
template<int DIN>
__global__ __launch_bounds__(64)
void pack_w(const float* __restrict__ Wself, const float* __restrict__ Wneigh,
            short* __restrict__ Wp)
{
    const int blk = blockIdx.x;
    const int ks  = blk >> 4, nt = blk & 15;
    const int l   = threadIdx.x;
    const int col = nt * 16 + (l & 15);
    const int k0  = ks * 32 + (l >> 4) * 8;

    bf16x8 hi, lo;
    #pragma unroll
    for (int e = 0; e < 8; ++e) {
        int k = k0 + e;
        float w = (k < DIN) ? Wself[k * 256 + col] : Wneigh[(k - DIN) * 256 + col];
        short h = f2bf(w);
        hi[e] = h;
        lo[e] = f2bf(w - bf2f(h));
    }
    *reinterpret_cast<bf16x8*>(Wp + (size_t)blk * 1024 + l * 8)       = hi;
    *reinterpret_cast<bf16x8*>(Wp + (size_t)blk * 1024 + 512 + l * 8) = lo;
}

// ---------------------------------------------------------------------------
// Fused SAGE layer, split-precision bf16 MFMA (16x16x32), DOUT = 256.
// Control flow identical to the R2 kernel that passed post-timing validation:
//   nb -> barrier -> gather-mean into LDS -> barrier -> single k-loop GEMM
// with self rows read from global INSIDE the k-loop (no prefetch reordering).
//   IN_BF16:  input features are bf16 (exact -> 2-term self MFMA)
//   OUT_BF16: write output as bf16
// ---------------------------------------------------------------------------
template<int DIN, int F, int RB, int NTW, bool IN_BF16, bool OUT_BF16, bool RELU>
__global__ __launch_bounds__(256)
void sage_mfma(const void* __restrict__ h_in_v,
               const int*   __restrict__ neigh,
               const short* __restrict__ Wp,
               const float* __restrict__ bias,
               void* __restrict__ h_out_v)
{
    constexpr int KS   = DIN / 16;          // k-steps over Ktot = 2*DIN (32 each)
    constexpr int KSH  = DIN / 32;          // self-half k-steps
    constexpr int LROW = DIN + 4;
    constexpr bool SPLIT_NT = (NTW < 16);
    constexpr float invF = 1.0f / F;

    __shared__ float An[RB][LROW];          // mean of neighbor rows (fp32)
    __shared__ int   nb[RB * F];

    const int  tid = threadIdx.x;
    const int  w   = tid >> 6, l = tid & 63;
    const int  lr  = l & 15, lk = l >> 4;
    const long r0  = (long)blockIdx.x * RB;
    const int  wrow = SPLIT_NT ? 0 : w * 16;
    const int  nt0  = SPLIT_NT ? w * NTW : 0;

    for (int p = tid; p < RB * F; p += 256)
        nb[p] = neigh[r0 * F + p];
    __syncthreads();                        // nb ready

    if constexpr (!IN_BF16) {
        // ---- gather + mean (fp32 rows) ----
        constexpr int QD = DIN / 4;
        const float* hin = (const float*)h_in_v;
        for (int p = tid; p < RB * QD; p += 256) {
            int m = p / QD, q = p - m * QD;
            float4 a = make_float4(0.f, 0.f, 0.f, 0.f);
            #pragma unroll
            for (int n = 0; n < F; ++n) {
                long idx = nb[m * F + n];
                float4 v = reinterpret_cast<const float4*>(hin + idx * DIN)[q];
                a.x += v.x; a.y += v.y; a.z += v.z; a.w += v.w;
            }
            a.x *= invF; a.y *= invF; a.z *= invF; a.w *= invF;
            *reinterpret_cast<float4*>(&An[m][q * 4]) = a;
        }
    } else {
        // ---- gather + mean (bf16 rows, fp32 accumulate) ----
        constexpr int NQ = DIN / 8;
        const short* hin = (const short*)h_in_v;
        for (int p = tid; p < RB * NQ; p += 256) {
            int m = p / NQ, c = p - m * NQ;
            float a[8] = {0.f,0.f,0.f,0.f,0.f,0.f,0.f,0.f};
            #pragma unroll
            for (int n = 0; n < F; ++n) {
                long idx = nb[m * F + n];
                bf16x8 v = *reinterpret_cast<const bf16x8*>(hin + idx * DIN + c * 8);
                #pragma unroll
                for (int e = 0; e < 8; ++e) a[e] += bf2f(v[e]);
            }
            #pragma unroll
            for (int e = 0; e < 8; ++e) a[e] *= invF;
            *reinterpret_cast<float4*>(&An[m][c * 8])     = make_float4(a[0],a[1],a[2],a[3]);
            *reinterpret_cast<float4*>(&An[m][c * 8 + 4]) = make_float4(a[4],a[5],a[6],a[7]);
        }
    }
    __syncthreads();                        // An ready

    // ---- GEMM: single k-loop, self half from global, neigh half from LDS ----
    const float* selfrowF = (const float*)h_in_v + (r0 + wrow + lr) * DIN;
    const short* selfrowB = (const short*)h_in_v + (r0 + wrow + lr) * DIN;
    const float* neighrow = &An[wrow + lr][0];

    f32x4 acc[NTW];
    #pragma unroll
    for (int j = 0; j < NTW; ++j) acc[j] = f32x4{0.f, 0.f, 0.f, 0.f};

    for (int ks = 0; ks < KS; ++ks) {
        bf16x8 ah, al;
        bool self_exact = false;
        if (ks < KSH) {
            if constexpr (IN_BF16) {
                ah = *reinterpret_cast<const bf16x8*>(selfrowB + ks * 32 + lk * 8);
                self_exact = true;
            } else {
                const int k0 = ks * 32 + lk * 8;
                float4 t0 = *reinterpret_cast<const float4*>(selfrowF + k0);
                float4 t1 = *reinterpret_cast<const float4*>(selfrowF + k0 + 4);
                float v[8] = {t0.x, t0.y, t0.z, t0.w, t1.x, t1.y, t1.z, t1.w};
                #pragma unroll
                for (int e = 0; e < 8; ++e) {
                    short h = f2bf(v[e]);
                    ah[e] = h;
                    al[e] = f2bf(v[e] - bf2f(h));
                }
            }
        } else {
            const int k0 = (ks - KSH) * 32 + lk * 8;
            float4 t0 = *reinterpret_cast<const float4*>(neighrow + k0);
            float4 t1 = *reinterpret_cast<const float4*>(neighrow + k0 + 4);
            float v[8] = {t0.x, t0.y, t0.z, t0.w, t1.x, t1.y, t1.z, t1.w};
            #pragma unroll
            for (int e = 0; e < 8; ++e) {
                short h = f2bf(v[e]);
                ah[e] = h;
                al[e] = f2bf(v[e] - bf2f(h));
            }
        }

        const bf16x8* wp = reinterpret_cast<const bf16x8*>(Wp) +
                           (size_t)(ks * 16 + nt0) * 128;
        #pragma unroll
        for (int j = 0; j < NTW; ++j) {
            bf16x8 bh = wp[j * 128 + l];
            bf16x8 bl = wp[j * 128 + 64 + l];
            acc[j] = __builtin_amdgcn_mfma_f32_16x16x32_bf16(ah, bh, acc[j], 0, 0, 0);
            if (!self_exact)
                acc[j] = __builtin_amdgcn_mfma_f32_16x16x32_bf16(al, bh, acc[j], 0, 0, 0);
            acc[j] = __builtin_amdgcn_mfma_f32_16x16x32_bf16(ah, bl, acc[j], 0, 0, 0);
        }
    }

    // ---- epilogue: bias (+relu); C/D: col=l&15, row=(l>>4)*4+r ----
    #pragma unroll
    for (int j = 0; j < NTW; ++j) {
        const int col = (nt0 + j) * 16 + lr;
        const float b = bias[col];
        #pragma unroll
        for (int r = 0; r < 4; ++r) {
            const long row = r0 + wrow + lk * 4 + r;
            float val = acc[j][r] + b;
            if (RELU) val = fmaxf(val, 0.f);
            if constexpr (OUT_BF16)
                ((short*)h_out_v)[row * 256 + col] = f2bf(val);
            else
                ((float*)h_out_v)[row * 256 + col] = val;
        }
    }
}

// ---------------------------------------------------------------------------
// Final layer: M=1024, DIN=256, F=5, DOUT=47, fp32 vector math (tiny).
// ---------------------------------------------------------------------------
__global__ __launch_bounds__(64)
void sage_out(const float* __restrict__ h_in,
              const int*   __restrict__ neigh,
              const float* __restrict__ Wself,
              const float* __restrict__ Wneigh,
              const float* __restrict__ bias,
              float* __restrict__ out)
{
    __shared__ float hs[256], hn[256];
    __shared__ int   nb[5];
    const int r = blockIdx.x, tid = threadIdx.x;

    if (tid < 5) nb[tid] = neigh[r * 5 + tid];
    __syncthreads();

    for (int k = tid; k < 256; k += 64) {
        hs[k] = h_in[(long)r * 256 + k];
        float a = 0.f;
        #pragma unroll
        for (int n = 0; n < 5; ++n) a += h_in[(long)nb[n] * 256 + k];
        hn[k] = a * 0.2f;
    }
    __syncthreads();

    if (tid < 47) {
        float acc = bias[tid];
        for (int k = 0; k < 256; ++k)
            acc += hs[k] * Wself[k * 47 + tid] + hn[k] * Wneigh[k * 47 + tid];
        out[r * 47 + tid] = acc;
    }
}

// ---------------------------------------------------------------------------
extern "C" void kernel_launch(void* const* d_in, const int* in_sizes, int n_in,
                              void* d_out, int out_size, void* d_ws, size_t ws_size,
                              hipStream_t stream)
{
    const float* x   = (const float*)d_in[0];
    const int*   n0  = (const int*)  d_in[1];
    const int*   n1  = (const int*)  d_in[2];
    const int*   n2  = (const int*)  d_in[3];
    const float* Ws0 = (const float*)d_in[4];
    const float* Wn0 = (const float*)d_in[5];
    const float* b0  = (const float*)d_in[6];
    const float* Ws1 = (const float*)d_in[7];
    const float* Wn1 = (const float*)d_in[8];
    const float* b1  = (const float*)d_in[9];
    const float* Ws2 = (const float*)d_in[10];
    const float* Wn2 = (const float*)d_in[11];
    const float* b2  = (const float*)d_in[12];
    float* out = (float*)d_out;

    // workspace layout
    short* h1  = (short*)d_ws;                            // 67584*256 bf16 = 34.6 MB
    float* h2  = (float*)(h1 + (size_t)67584 * 256);      //  6144*256 f32  =  6.3 MB
    short* Wp0 = (short*)(h2 + (size_t)6144 * 256);       //  8*16*1024 bf16 = 256 KB
    short* Wp1 = Wp0 + (size_t)8 * 16 * 1024;             // 16*16*1024 bf16 = 512 KB

    pack_w<128><<<8 * 16,  64, 0, stream>>>(Ws0, Wn0, Wp0);
    pack_w<256><<<16 * 16, 64, 0, stream>>>(Ws1, Wn1, Wp1);

    // layer 0: fp32 in, bf16 out; RB=64 (4 waves x 16-row strips, all 16 nt)
    sage_mfma<128, 15, 64, 16, false, true,  true><<<67584 / 64, 256, 0, stream>>>(x,  n0, Wp0, b0, h1);
    // layer 1: bf16 in, fp32 out; RB=16 shared rows, nt split 4/wave
    sage_mfma<256, 10, 16, 4,  true,  false, true><<<6144 / 16,  256, 0, stream>>>(h1, n1, Wp1, b1, h2);
    // layer 2
    sage_out<<<1024, 64, 0, stream>>>(h2, n2, Ws2, Wn2, b2, out);
}

// Round 6
// 184.670 us; speedup vs baseline: 1.0248x; 1.0248x over previous
//
#include <hip/hip_runtime.h>

using bf16x8 = __attribute__((ext_vector_type(8))) short;
using f32x4  = __attribute__((ext_vector_type(4))) float;

// ---- bf16 helpers (RNE) ----------------------------------------------------
__device__ __forceinline__ short f2bf(float x) {
    union { float f; unsigned u; } v; v.f = x;
    unsigned r = v.u + 0x7fffu + ((v.u >> 16) & 1u);
    return (short)(r >> 16);
}
__device__ __forceinline__ float bf2f(short h) {
    union { unsigned u; float f; } v; v.u = ((unsigned)(unsigned short)h) << 16;
    return v.f;
}

// ---------------------------------------------------------------------------
// Pack Wself/Wneigh (fp32, [DIN][256] each) into MFMA B-fragment order,
// split hi/lo bf16.  Ktot = 2*DIN (self rows then neigh rows).
// blk = ks*16+nt:  Wp[blk*1024 + l*8]=hi frag,  Wp[blk*1024 + 512 + l*8]=lo.
// (lo plane currently unread by the GEMM — kept for layout stability.)
// B-frag: lane l holds B[k = ks*32 + (l>>4)*8 + e][n = nt*16 + (l&15)]
// ---------------------------------------------------------------------------
template<int DIN>
__global__ __launch_bounds__(64)
void pack_w(const float* __restrict__ Wself, const float* __restrict__ Wneigh,
            short* __restrict__ Wp)
{
    const int blk = blockIdx.x;
    const int ks  = blk >> 4, nt = blk & 15;
    const int l   = threadIdx.x;
    const int col = nt * 16 + (l & 15);
    const int k0  = ks * 32 + (l >> 4) * 8;

    bf16x8 hi, lo;
    #pragma unroll
    for (int e = 0; e < 8; ++e) {
        int k = k0 + e;
        float w = (k < DIN) ? Wself[k * 256 + col] : Wneigh[(k - DIN) * 256 + col];
        short h = f2bf(w);
        hi[e] = h;
        lo[e] = f2bf(w - bf2f(h));
    }
    *reinterpret_cast<bf16x8*>(Wp + (size_t)blk * 1024 + l * 8)       = hi;
    *reinterpret_cast<bf16x8*>(Wp + (size_t)blk * 1024 + 512 + l * 8) = lo;
}

// ---------------------------------------------------------------------------
// Fused SAGE layer, bf16 MFMA (16x16x32) with A-side split correction, DOUT=256.
// Control flow identical to the R5 kernel that passed post-timing validation:
//   nb -> barrier -> gather-mean into LDS -> barrier -> single k-loop GEMM
// W enters as bf16-hi only (W-lo term dropped); inexact A gets al*bh term.
//   IN_BF16:  input features are bf16 (exact -> 1-term self MFMA)
//   OUT_BF16: write output as bf16
// ---------------------------------------------------------------------------
template<int DIN, int F, int RB, int NTW, bool IN_BF16, bool OUT_BF16, bool RELU>
__global__ __launch_bounds__(256)
void sage_mfma(const void* __restrict__ h_in_v,
               const int*   __restrict__ neigh,
               const short* __restrict__ Wp,
               const float* __restrict__ bias,
               void* __restrict__ h_out_v)
{
    constexpr int KS   = DIN / 16;          // k-steps over Ktot = 2*DIN (32 each)
    constexpr int KSH  = DIN / 32;          // self-half k-steps
    constexpr int LROW = DIN + 4;
    constexpr bool SPLIT_NT = (NTW < 16);
    constexpr float invF = 1.0f / F;

    __shared__ float An[RB][LROW];          // mean of neighbor rows (fp32)
    __shared__ int   nb[RB * F];

    const int  tid = threadIdx.x;
    const int  w   = tid >> 6, l = tid & 63;
    const int  lr  = l & 15, lk = l >> 4;
    const long r0  = (long)blockIdx.x * RB;
    const int  wrow = SPLIT_NT ? 0 : w * 16;
    const int  nt0  = SPLIT_NT ? w * NTW : 0;

    for (int p = tid; p < RB * F; p += 256)
        nb[p] = neigh[r0 * F + p];
    __syncthreads();                        // nb ready

    if constexpr (!IN_BF16) {
        // ---- gather + mean (fp32 rows) ----
        constexpr int QD = DIN / 4;
        const float* hin = (const float*)h_in_v;
        for (int p = tid; p < RB * QD; p += 256) {
            int m = p / QD, q = p - m * QD;
            float4 a = make_float4(0.f, 0.f, 0.f, 0.f);
            #pragma unroll
            for (int n = 0; n < F; ++n) {
                long idx = nb[m * F + n];
                float4 v = reinterpret_cast<const float4*>(hin + idx * DIN)[q];
                a.x += v.x; a.y += v.y; a.z += v.z; a.w += v.w;
            }
            a.x *= invF; a.y *= invF; a.z *= invF; a.w *= invF;
            *reinterpret_cast<float4*>(&An[m][q * 4]) = a;
        }
    } else {
        // ---- gather + mean (bf16 rows, fp32 accumulate) ----
        constexpr int NQ = DIN / 8;
        const short* hin = (const short*)h_in_v;
        for (int p = tid; p < RB * NQ; p += 256) {
            int m = p / NQ, c = p - m * NQ;
            float a[8] = {0.f,0.f,0.f,0.f,0.f,0.f,0.f,0.f};
            #pragma unroll
            for (int n = 0; n < F; ++n) {
                long idx = nb[m * F + n];
                bf16x8 v = *reinterpret_cast<const bf16x8*>(hin + idx * DIN + c * 8);
                #pragma unroll
                for (int e = 0; e < 8; ++e) a[e] += bf2f(v[e]);
            }
            #pragma unroll
            for (int e = 0; e < 8; ++e) a[e] *= invF;
            *reinterpret_cast<float4*>(&An[m][c * 8])     = make_float4(a[0],a[1],a[2],a[3]);
            *reinterpret_cast<float4*>(&An[m][c * 8 + 4]) = make_float4(a[4],a[5],a[6],a[7]);
        }
    }
    __syncthreads();                        // An ready

    // ---- GEMM: single k-loop, self half from global, neigh half from LDS ----
    const float* selfrowF = (const float*)h_in_v + (r0 + wrow + lr) * DIN;
    const short* selfrowB = (const short*)h_in_v + (r0 + wrow + lr) * DIN;
    const float* neighrow = &An[wrow + lr][0];

    f32x4 acc[NTW];
    #pragma unroll
    for (int j = 0; j < NTW; ++j) acc[j] = f32x4{0.f, 0.f, 0.f, 0.f};

    for (int ks = 0; ks < KS; ++ks) {
        bf16x8 ah, al;
        bool self_exact = false;
        if (ks < KSH) {
            if constexpr (IN_BF16) {
                ah = *reinterpret_cast<const bf16x8*>(selfrowB + ks * 32 + lk * 8);
                self_exact = true;
            } else {
                const int k0 = ks * 32 + lk * 8;
                float4 t0 = *reinterpret_cast<const float4*>(selfrowF + k0);
                float4 t1 = *reinterpret_cast<const float4*>(selfrowF + k0 + 4);
                float v[8] = {t0.x, t0.y, t0.z, t0.w, t1.x, t1.y, t1.z, t1.w};
                #pragma unroll
                for (int e = 0; e < 8; ++e) {
                    short h = f2bf(v[e]);
                    ah[e] = h;
                    al[e] = f2bf(v[e] - bf2f(h));
                }
            }
        } else {
            const int k0 = (ks - KSH) * 32 + lk * 8;
            float4 t0 = *reinterpret_cast<const float4*>(neighrow + k0);
            float4 t1 = *reinterpret_cast<const float4*>(neighrow + k0 + 4);
            float v[8] = {t0.x, t0.y, t0.z, t0.w, t1.x, t1.y, t1.z, t1.w};
            #pragma unroll
            for (int e = 0; e < 8; ++e) {
                short h = f2bf(v[e]);
                ah[e] = h;
                al[e] = f2bf(v[e] - bf2f(h));
            }
        }

        const bf16x8* wp = reinterpret_cast<const bf16x8*>(Wp) +
                           (size_t)(ks * 16 + nt0) * 128;
        #pragma unroll
        for (int j = 0; j < NTW; ++j) {
            bf16x8 bh = wp[j * 128 + l];
            acc[j] = __builtin_amdgcn_mfma_f32_16x16x32_bf16(ah, bh, acc[j], 0, 0, 0);
            if (!self_exact)
                acc[j] = __builtin_amdgcn_mfma_f32_16x16x32_bf16(al, bh, acc[j], 0, 0, 0);
        }
    }

    // ---- epilogue: bias (+relu); C/D: col=l&15, row=(l>>4)*4+r ----
    #pragma unroll
    for (int j = 0; j < NTW; ++j) {
        const int col = (nt0 + j) * 16 + lr;
        const float b = bias[col];
        #pragma unroll
        for (int r = 0; r < 4; ++r) {
            const long row = r0 + wrow + lk * 4 + r;
            float val = acc[j][r] + b;
            if (RELU) val = fmaxf(val, 0.f);
            if constexpr (OUT_BF16)
                ((short*)h_out_v)[row * 256 + col] = f2bf(val);
            else
                ((float*)h_out_v)[row * 256 + col] = val;
        }
    }
}

// ---------------------------------------------------------------------------
// Final layer: M=1024, DIN=256, F=5, DOUT=47, fp32 vector math (tiny).
// ---------------------------------------------------------------------------
__global__ __launch_bounds__(64)
void sage_out(const float* __restrict__ h_in,
              const int*   __restrict__ neigh,
              const float* __restrict__ Wself,
              const float* __restrict__ Wneigh,
              const float* __restrict__ bias,
              float* __restrict__ out)
{
    __shared__ float hs[256], hn[256];
    __shared__ int   nb[5];
    const int r = blockIdx.x, tid = threadIdx.x;

    if (tid < 5) nb[tid] = neigh[r * 5 + tid];
    __syncthreads();

    for (int k = tid; k < 256; k += 64) {
        hs[k] = h_in[(long)r * 256 + k];
        float a = 0.f;
        #pragma unroll
        for (int n = 0; n < 5; ++n) a += h_in[(long)nb[n] * 256 + k];
        hn[k] = a * 0.2f;
    }
    __syncthreads();

    if (tid < 47) {
        float acc = bias[tid];
        for (int k = 0; k < 256; ++k)
            acc += hs[k] * Wself[k * 47 + tid] + hn[k] * Wneigh[k * 47 + tid];
        out[r * 47 + tid] = acc;
    }
}

// ---------------------------------------------------------------------------
extern "C" void kernel_launch(void* const* d_in, const int* in_sizes, int n_in,
                              void* d_out, int out_size, void* d_ws, size_t ws_size,
                              hipStream_t stream)
{
    const float* x   = (const float*)d_in[0];
    const int*   n0  = (const int*)  d_in[1];
    const int*   n1  = (const int*)  d_in[2];
    const int*   n2  = (const int*)  d_in[3];
    const float* Ws0 = (const float*)d_in[4];
    const float* Wn0 = (const float*)d_in[5];
    const float* b0  = (const float*)d_in[6];
    const float* Ws1 = (const float*)d_in[7];
    const float* Wn1 = (const float*)d_in[8];
    const float* b1  = (const float*)d_in[9];
    const float* Ws2 = (const float*)d_in[10];
    const float* Wn2 = (const float*)d_in[11];
    const float* b2  = (const float*)d_in[12];
    float* out = (float*)d_out;

    // workspace layout
    short* h1  = (short*)d_ws;                            // 67584*256 bf16 = 34.6 MB
    float* h2  = (float*)(h1 + (size_t)67584 * 256);      //  6144*256 f32  =  6.3 MB
    short* Wp0 = (short*)(h2 + (size_t)6144 * 256);       //  8*16*1024 bf16 = 256 KB
    short* Wp1 = Wp0 + (size_t)8 * 16 * 1024;             // 16*16*1024 bf16 = 512 KB

    pack_w<128><<<8 * 16,  64, 0, stream>>>(Ws0, Wn0, Wp0);
    pack_w<256><<<16 * 16, 64, 0, stream>>>(Ws1, Wn1, Wp1);

    // layer 0: fp32 in, bf16 out; RB=64 (4 waves x 16-row strips, all 16 nt)
    sage_mfma<128, 15, 64, 16, false, true,  true><<<67584 / 64, 256, 0, stream>>>(x,  n0, Wp0, b0, h1);
    // layer 1: bf16 in, fp32 out; RB=16 shared rows, nt split 4/wave
    sage_mfma<256, 10, 16, 4,  true,  false, true><<<6144 / 16,  256, 0, stream>>>(h1, n1, Wp1, b1, h2);
    // layer 2
    sage_out<<<1024, 64, 0, stream>>>(h2, n2, Ws2, Wn2, b2, out);
}

// Round 7
// 151.099 us; speedup vs baseline: 1.2524x; 1.2222x over previous
//
#include <hip/hip_runtime.h>

using bf16x8 = __attribute__((ext_vector_type(8))) short;
using f32x4  = __attribute__((ext_vector_type(4))) float;

// ---- bf16 helpers (RNE) ----------------------------------------------------
__device__ __forceinline__ short f2bf(float x) {
    union { float f; unsigned u; } v; v.f = x;
    unsigned r = v.u + 0x7fffu + ((v.u >> 16) & 1u);
    return (short)(r >> 16);
}
__device__ __forceinline__ float bf2f(short h) {
    union { unsigned u; float f; } v; v.u = ((unsigned)(unsigned short)h) << 16;
    return v.f;
}

// ---------------------------------------------------------------------------
// Pack Wself/Wneigh (fp32, [DIN][256] each) into MFMA B-fragment order,
// bf16 hi only (compact: 512 shorts per k-step x col-block).
// blk = ks*16+nt:  Wp[blk*512 + l*8] = hi frag (8 bf16).
// B-frag: lane l holds B[k = ks*32 + (l>>4)*8 + e][n = nt*16 + (l&15)]
// Both layers packed by ONE kernel launch (block-uniform branch).
// ---------------------------------------------------------------------------
template<int DIN>
__device__ __forceinline__ void pack_one(int blk, const float* __restrict__ Wself,
                                         const float* __restrict__ Wneigh,
                                         short* __restrict__ Wp, int l)
{
    const int ks  = blk >> 4, nt = blk & 15;
    const int col = nt * 16 + (l & 15);
    const int k0  = ks * 32 + (l >> 4) * 8;

    bf16x8 hi;
    #pragma unroll
    for (int e = 0; e < 8; ++e) {
        int k = k0 + e;
        float w = (k < DIN) ? Wself[k * 256 + col] : Wneigh[(k - DIN) * 256 + col];
        hi[e] = f2bf(w);
    }
    *reinterpret_cast<bf16x8*>(Wp + (size_t)blk * 512 + l * 8) = hi;
}

__global__ __launch_bounds__(64)
void pack_w_all(const float* __restrict__ Ws0, const float* __restrict__ Wn0,
                short* __restrict__ Wp0,
                const float* __restrict__ Ws1, const float* __restrict__ Wn1,
                short* __restrict__ Wp1)
{
    const int b = blockIdx.x, l = threadIdx.x;
    if (b < 128) pack_one<128>(b, Ws0, Wn0, Wp0, l);        // 8 ks x 16 nt
    else         pack_one<256>(b - 128, Ws1, Wn1, Wp1, l);  // 16 ks x 16 nt
}

// ---------------------------------------------------------------------------
// Fused SAGE layer, bf16 MFMA (16x16x32) with A-side split correction, DOUT=256.
// Sync structure identical to the validated R5/R6 kernel:
//   nb -> barrier -> gather-mean into LDS -> barrier -> single k-loop GEMM
// Wave mapping generalized: WROWS = RB/16 row-strips, WCOLS = 16/NTW col groups,
// WROWS*WCOLS = 4 waves.  wrow = (w % WROWS)*16, nt0 = (w / WROWS)*NTW.
//   IN_BF16:  input features are bf16 (exact -> 1-term self MFMA)
//   OUT_BF16: write output as bf16
// ---------------------------------------------------------------------------
template<int DIN, int F, int RB, int NTW, bool IN_BF16, bool OUT_BF16, bool RELU>
__global__ __launch_bounds__(256)
void sage_mfma(const void* __restrict__ h_in_v,
               const int*   __restrict__ neigh,
               const short* __restrict__ Wp,
               const float* __restrict__ bias,
               void* __restrict__ h_out_v)
{
    constexpr int KS    = DIN / 16;         // k-steps over Ktot = 2*DIN (32 each)
    constexpr int KSH   = DIN / 32;         // self-half k-steps
    constexpr int LROW  = DIN + 4;
    constexpr int WROWS = RB / 16;
    constexpr int WCOLS = 16 / NTW;
    static_assert(WROWS * WCOLS == 4, "4 waves");
    constexpr float invF = 1.0f / F;

    __shared__ float An[RB][LROW];          // mean of neighbor rows (fp32)
    __shared__ int   nb[RB * F];

    const int  tid = threadIdx.x;
    const int  w   = tid >> 6, l = tid & 63;
    const int  lr  = l & 15, lk = l >> 4;
    const long r0  = (long)blockIdx.x * RB;
    const int  wrow = (w % WROWS) * 16;
    const int  nt0  = (w / WROWS) * NTW;

    for (int p = tid; p < RB * F; p += 256)
        nb[p] = neigh[r0 * F + p];
    __syncthreads();                        // nb ready

    if constexpr (!IN_BF16) {
        // ---- gather + mean (fp32 rows) ----
        constexpr int QD = DIN / 4;
        const float* hin = (const float*)h_in_v;
        for (int p = tid; p < RB * QD; p += 256) {
            int m = p / QD, q = p - m * QD;
            float4 a = make_float4(0.f, 0.f, 0.f, 0.f);
            #pragma unroll
            for (int n = 0; n < F; ++n) {
                long idx = nb[m * F + n];
                float4 v = reinterpret_cast<const float4*>(hin + idx * DIN)[q];
                a.x += v.x; a.y += v.y; a.z += v.z; a.w += v.w;
            }
            a.x *= invF; a.y *= invF; a.z *= invF; a.w *= invF;
            *reinterpret_cast<float4*>(&An[m][q * 4]) = a;
        }
    } else {
        // ---- gather + mean (bf16 rows, fp32 accumulate) ----
        constexpr int NQ = DIN / 8;
        const short* hin = (const short*)h_in_v;
        for (int p = tid; p < RB * NQ; p += 256) {
            int m = p / NQ, c = p - m * NQ;
            float a[8] = {0.f,0.f,0.f,0.f,0.f,0.f,0.f,0.f};
            #pragma unroll
            for (int n = 0; n < F; ++n) {
                long idx = nb[m * F + n];
                bf16x8 v = *reinterpret_cast<const bf16x8*>(hin + idx * DIN + c * 8);
                #pragma unroll
                for (int e = 0; e < 8; ++e) a[e] += bf2f(v[e]);
            }
            #pragma unroll
            for (int e = 0; e < 8; ++e) a[e] *= invF;
            *reinterpret_cast<float4*>(&An[m][c * 8])     = make_float4(a[0],a[1],a[2],a[3]);
            *reinterpret_cast<float4*>(&An[m][c * 8 + 4]) = make_float4(a[4],a[5],a[6],a[7]);
        }
    }
    __syncthreads();                        // An ready

    // ---- GEMM: single k-loop, self half from global, neigh half from LDS ----
    const float* selfrowF = (const float*)h_in_v + (r0 + wrow + lr) * DIN;
    const short* selfrowB = (const short*)h_in_v + (r0 + wrow + lr) * DIN;
    const float* neighrow = &An[wrow + lr][0];

    f32x4 acc[NTW];
    #pragma unroll
    for (int j = 0; j < NTW; ++j) acc[j] = f32x4{0.f, 0.f, 0.f, 0.f};

    for (int ks = 0; ks < KS; ++ks) {
        bf16x8 ah, al;
        bool self_exact = false;
        if (ks < KSH) {
            if constexpr (IN_BF16) {
                ah = *reinterpret_cast<const bf16x8*>(selfrowB + ks * 32 + lk * 8);
                self_exact = true;
            } else {
                const int k0 = ks * 32 + lk * 8;
                float4 t0 = *reinterpret_cast<const float4*>(selfrowF + k0);
                float4 t1 = *reinterpret_cast<const float4*>(selfrowF + k0 + 4);
                float v[8] = {t0.x, t0.y, t0.z, t0.w, t1.x, t1.y, t1.z, t1.w};
                #pragma unroll
                for (int e = 0; e < 8; ++e) {
                    short h = f2bf(v[e]);
                    ah[e] = h;
                    al[e] = f2bf(v[e] - bf2f(h));
                }
            }
        } else {
            const int k0 = (ks - KSH) * 32 + lk * 8;
            float4 t0 = *reinterpret_cast<const float4*>(neighrow + k0);
            float4 t1 = *reinterpret_cast<const float4*>(neighrow + k0 + 4);
            float v[8] = {t0.x, t0.y, t0.z, t0.w, t1.x, t1.y, t1.z, t1.w};
            #pragma unroll
            for (int e = 0; e < 8; ++e) {
                short h = f2bf(v[e]);
                ah[e] = h;
                al[e] = f2bf(v[e] - bf2f(h));
            }
        }

        // compact Wp: 64 bf16x8 frags per (ks,nt) block
        const bf16x8* wp = reinterpret_cast<const bf16x8*>(Wp) +
                           (size_t)(ks * 16 + nt0) * 64;
        #pragma unroll
        for (int j = 0; j < NTW; ++j) {
            bf16x8 bh = wp[j * 64 + l];
            acc[j] = __builtin_amdgcn_mfma_f32_16x16x32_bf16(ah, bh, acc[j], 0, 0, 0);
            if (!self_exact)
                acc[j] = __builtin_amdgcn_mfma_f32_16x16x32_bf16(al, bh, acc[j], 0, 0, 0);
        }
    }

    // ---- epilogue: bias (+relu); C/D: col=l&15, row=(l>>4)*4+r ----
    #pragma unroll
    for (int j = 0; j < NTW; ++j) {
        const int col = (nt0 + j) * 16 + lr;
        const float b = bias[col];
        #pragma unroll
        for (int r = 0; r < 4; ++r) {
            const long row = r0 + wrow + lk * 4 + r;
            float val = acc[j][r] + b;
            if (RELU) val = fmaxf(val, 0.f);
            if constexpr (OUT_BF16)
                ((short*)h_out_v)[row * 256 + col] = f2bf(val);
            else
                ((float*)h_out_v)[row * 256 + col] = val;
        }
    }
}

// ---------------------------------------------------------------------------
// Final layer: M=1024, DIN=256, F=5, DOUT=47, fp32 vector math (tiny).
// ---------------------------------------------------------------------------
__global__ __launch_bounds__(64)
void sage_out(const float* __restrict__ h_in,
              const int*   __restrict__ neigh,
              const float* __restrict__ Wself,
              const float* __restrict__ Wneigh,
              const float* __restrict__ bias,
              float* __restrict__ out)
{
    __shared__ float hs[256], hn[256];
    __shared__ int   nb[5];
    const int r = blockIdx.x, tid = threadIdx.x;

    if (tid < 5) nb[tid] = neigh[r * 5 + tid];
    __syncthreads();

    for (int k = tid; k < 256; k += 64) {
        hs[k] = h_in[(long)r * 256 + k];
        float a = 0.f;
        #pragma unroll
        for (int n = 0; n < 5; ++n) a += h_in[(long)nb[n] * 256 + k];
        hn[k] = a * 0.2f;
    }
    __syncthreads();

    if (tid < 47) {
        float acc = bias[tid];
        for (int k = 0; k < 256; ++k)
            acc += hs[k] * Wself[k * 47 + tid] + hn[k] * Wneigh[k * 47 + tid];
        out[r * 47 + tid] = acc;
    }
}

// ---------------------------------------------------------------------------
extern "C" void kernel_launch(void* const* d_in, const int* in_sizes, int n_in,
                              void* d_out, int out_size, void* d_ws, size_t ws_size,
                              hipStream_t stream)
{
    const float* x   = (const float*)d_in[0];
    const int*   n0  = (const int*)  d_in[1];
    const int*   n1  = (const int*)  d_in[2];
    const int*   n2  = (const int*)  d_in[3];
    const float* Ws0 = (const float*)d_in[4];
    const float* Wn0 = (const float*)d_in[5];
    const float* b0  = (const float*)d_in[6];
    const float* Ws1 = (const float*)d_in[7];
    const float* Wn1 = (const float*)d_in[8];
    const float* b1  = (const float*)d_in[9];
    const float* Ws2 = (const float*)d_in[10];
    const float* Wn2 = (const float*)d_in[11];
    const float* b2  = (const float*)d_in[12];
    float* out = (float*)d_out;

    // workspace layout
    short* h1  = (short*)d_ws;                            // 67584*256 bf16 = 34.6 MB
    float* h2  = (float*)(h1 + (size_t)67584 * 256);      //  6144*256 f32  =  6.3 MB
    short* Wp0 = (short*)(h2 + (size_t)6144 * 256);       // 128*512 bf16 = 128 KB
    short* Wp1 = Wp0 + (size_t)128 * 512;                 // 256*512 bf16 = 256 KB

    // single pack launch for both layers (128 + 256 blocks)
    pack_w_all<<<384, 64, 0, stream>>>(Ws0, Wn0, Wp0, Ws1, Wn1, Wp1);

    // layer 0: fp32 in, bf16 out; RB=32 (2 row-strips x 2 col-groups, NTW=8)
    //          2112 blocks, 18.8 KB LDS -> up to 8 blocks/CU
    sage_mfma<128, 15, 32, 8, false, true,  true><<<67584 / 32, 256, 0, stream>>>(x,  n0, Wp0, b0, h1);
    // layer 1: bf16 in, fp32 out; RB=16 shared rows, nt split 4/wave
    sage_mfma<256, 10, 16, 4,  true,  false, true><<<6144 / 16,  256, 0, stream>>>(h1, n1, Wp1, b1, h2);
    // layer 2
    sage_out<<<1024, 64, 0, stream>>>(h2, n2, Ws2, Wn2, b2, out);
}

// Round 8
// 140.636 us; speedup vs baseline: 1.3456x; 1.0744x over previous
//
#include <hip/hip_runtime.h>

using bf16x8 = __attribute__((ext_vector_type(8))) short;
using f32x4  = __attribute__((ext_vector_type(4))) float;

// ---- bf16 helpers (RNE) ----------------------------------------------------
__device__ __forceinline__ short f2bf(float x) {
    union { float f; unsigned u; } v; v.f = x;
    unsigned r = v.u + 0x7fffu + ((v.u >> 16) & 1u);
    return (short)(r >> 16);
}
__device__ __forceinline__ float bf2f(short h) {
    union { unsigned u; float f; } v; v.u = ((unsigned)(unsigned short)h) << 16;
    return v.f;
}

// ---------------------------------------------------------------------------
// Demand-set construction for layer 0: a row r of h1 is needed iff r < 6144
// (layer-1 self rows) or r appears in neigh1. Mask -> atomic compaction.
// List ORDER is nondeterministic; the SET (and thus all h1 values and the
// final output) is deterministic.
// ---------------------------------------------------------------------------
__global__ __launch_bounds__(256)
void k_clear(unsigned* __restrict__ mask, unsigned* __restrict__ count, int n)
{
    int i = blockIdx.x * 256 + threadIdx.x;
    if (i < n) mask[i] = 0;
    if (i == 0) *count = 0;
}

// exactly 6144 + 61440 = 67584 threads
__global__ __launch_bounds__(256)
void k_mark(const int* __restrict__ neigh1, unsigned* __restrict__ mask)
{
    int j = blockIdx.x * 256 + threadIdx.x;
    if (j < 6144) mask[j] = 1;
    else if (j < 67584) mask[neigh1[j - 6144]] = 1;
}

__global__ __launch_bounds__(256)
void k_compact(const unsigned* __restrict__ mask, unsigned* __restrict__ list,
               unsigned* __restrict__ count, int n)
{
    int i = blockIdx.x * 256 + threadIdx.x;
    if (i < n && mask[i]) list[atomicAdd(count, 1u)] = i;
}

// ---------------------------------------------------------------------------
// Pack Wself/Wneigh (fp32, [DIN][256] each) into MFMA B-fragment order,
// bf16 hi only.  blk = ks*16+nt:  Wp[blk*512 + l*8] = frag (8 bf16).
// B-frag: lane l holds B[k = ks*32 + (l>>4)*8 + e][n = nt*16 + (l&15)]
// ---------------------------------------------------------------------------
template<int DIN>
__device__ __forceinline__ void pack_one(int blk, const float* __restrict__ Wself,
                                         const float* __restrict__ Wneigh,
                                         short* __restrict__ Wp, int l)
{
    const int ks  = blk >> 4, nt = blk & 15;
    const int col = nt * 16 + (l & 15);
    const int k0  = ks * 32 + (l >> 4) * 8;

    bf16x8 hi;
    #pragma unroll
    for (int e = 0; e < 8; ++e) {
        int k = k0 + e;
        float w = (k < DIN) ? Wself[k * 256 + col] : Wneigh[(k - DIN) * 256 + col];
        hi[e] = f2bf(w);
    }
    *reinterpret_cast<bf16x8*>(Wp + (size_t)blk * 512 + l * 8) = hi;
}

__global__ __launch_bounds__(64)
void pack_w_all(const float* __restrict__ Ws0, const float* __restrict__ Wn0,
                short* __restrict__ Wp0,
                const float* __restrict__ Ws1, const float* __restrict__ Wn1,
                short* __restrict__ Wp1)
{
    const int b = blockIdx.x, l = threadIdx.x;
    if (b < 128) pack_one<128>(b, Ws0, Wn0, Wp0, l);        // 8 ks x 16 nt
    else         pack_one<256>(b - 128, Ws1, Wn1, Wp1, l);  // 16 ks x 16 nt
}

// ---------------------------------------------------------------------------
// Fused SAGE layer, bf16 MFMA (16x16x32) with A-side split correction, DOUT=256.
// Validated phase structure: [rid stage ->] nb -> barrier -> gather-mean ->
// barrier -> single k-loop GEMM -> epilogue.
//   COMPACT:  rows come from list[0..count) instead of 0..M (demand-driven)
//   IN_BF16:  input features are bf16 (exact -> 1-term self MFMA)
//   OUT_BF16: write output as bf16
// ---------------------------------------------------------------------------
template<int DIN, int F, int RB, int NTW, bool COMPACT, bool IN_BF16, bool OUT_BF16, bool RELU>
__global__ __launch_bounds__(256)
void sage_mfma(const void* __restrict__ h_in_v,
               const int*   __restrict__ neigh,
               const short* __restrict__ Wp,
               const float* __restrict__ bias,
               void* __restrict__ h_out_v,
               const unsigned* __restrict__ list,
               const unsigned* __restrict__ count)
{
    constexpr int KS    = DIN / 16;         // k-steps over Ktot = 2*DIN (32 each)
    constexpr int KSH   = DIN / 32;         // self-half k-steps
    constexpr int LROW  = DIN + 4;
    constexpr int WROWS = RB / 16;
    constexpr int WCOLS = 16 / NTW;
    static_assert(WROWS * WCOLS == 4, "4 waves");
    constexpr float invF = 1.0f / F;

    __shared__ float    An[RB][LROW];       // mean of neighbor rows (fp32)
    __shared__ int      nb[RB * F];
    __shared__ unsigned rids[RB];
    __shared__ unsigned scnt;

    const int  tid = threadIdx.x;
    const int  w   = tid >> 6, l = tid & 63;
    const int  lr  = l & 15, lk = l >> 4;
    const long r0  = (long)blockIdx.x * RB;
    const int  wrow = (w % WROWS) * 16;
    const int  nt0  = (w / WROWS) * NTW;

    if constexpr (COMPACT) {
        if (tid == 0) scnt = *count;
        __syncthreads();
        if (r0 >= (long)scnt) return;       // block-uniform early exit
        for (int p = tid; p < RB; p += 256)
            rids[p] = (r0 + p < (long)scnt) ? list[r0 + p] : list[0];
        __syncthreads();                    // rids ready
        for (int p = tid; p < RB * F; p += 256)
            nb[p] = neigh[(long)rids[p / F] * F + (p % F)];
    } else {
        for (int p = tid; p < RB * F; p += 256)
            nb[p] = neigh[r0 * F + p];
    }
    __syncthreads();                        // nb ready

    if constexpr (!IN_BF16) {
        // ---- gather + mean (fp32 rows) ----
        constexpr int QD = DIN / 4;
        const float* hin = (const float*)h_in_v;
        for (int p = tid; p < RB * QD; p += 256) {
            int m = p / QD, q = p - m * QD;
            float4 a = make_float4(0.f, 0.f, 0.f, 0.f);
            #pragma unroll
            for (int n = 0; n < F; ++n) {
                long idx = nb[m * F + n];
                float4 v = reinterpret_cast<const float4*>(hin + idx * DIN)[q];
                a.x += v.x; a.y += v.y; a.z += v.z; a.w += v.w;
            }
            a.x *= invF; a.y *= invF; a.z *= invF; a.w *= invF;
            *reinterpret_cast<float4*>(&An[m][q * 4]) = a;
        }
    } else {
        // ---- gather + mean (bf16 rows, fp32 accumulate) ----
        constexpr int NQ = DIN / 8;
        const short* hin = (const short*)h_in_v;
        for (int p = tid; p < RB * NQ; p += 256) {
            int m = p / NQ, c = p - m * NQ;
            float a[8] = {0.f,0.f,0.f,0.f,0.f,0.f,0.f,0.f};
            #pragma unroll
            for (int n = 0; n < F; ++n) {
                long idx = nb[m * F + n];
                bf16x8 v = *reinterpret_cast<const bf16x8*>(hin + idx * DIN + c * 8);
                #pragma unroll
                for (int e = 0; e < 8; ++e) a[e] += bf2f(v[e]);
            }
            #pragma unroll
            for (int e = 0; e < 8; ++e) a[e] *= invF;
            *reinterpret_cast<float4*>(&An[m][c * 8])     = make_float4(a[0],a[1],a[2],a[3]);
            *reinterpret_cast<float4*>(&An[m][c * 8 + 4]) = make_float4(a[4],a[5],a[6],a[7]);
        }
    }
    __syncthreads();                        // An ready

    // ---- GEMM: single k-loop, self half from global, neigh half from LDS ----
    const long selfrid = COMPACT ? (long)rids[wrow + lr] : (r0 + wrow + lr);
    const float* selfrowF = (const float*)h_in_v + selfrid * DIN;
    const short* selfrowB = (const short*)h_in_v + selfrid * DIN;
    const float* neighrow = &An[wrow + lr][0];

    f32x4 acc[NTW];
    #pragma unroll
    for (int j = 0; j < NTW; ++j) acc[j] = f32x4{0.f, 0.f, 0.f, 0.f};

    for (int ks = 0; ks < KS; ++ks) {
        bf16x8 ah, al;
        bool self_exact = false;
        if (ks < KSH) {
            if constexpr (IN_BF16) {
                ah = *reinterpret_cast<const bf16x8*>(selfrowB + ks * 32 + lk * 8);
                self_exact = true;
            } else {
                const int k0 = ks * 32 + lk * 8;
                float4 t0 = *reinterpret_cast<const float4*>(selfrowF + k0);
                float4 t1 = *reinterpret_cast<const float4*>(selfrowF + k0 + 4);
                float v[8] = {t0.x, t0.y, t0.z, t0.w, t1.x, t1.y, t1.z, t1.w};
                #pragma unroll
                for (int e = 0; e < 8; ++e) {
                    short h = f2bf(v[e]);
                    ah[e] = h;
                    al[e] = f2bf(v[e] - bf2f(h));
                }
            }
        } else {
            const int k0 = (ks - KSH) * 32 + lk * 8;
            float4 t0 = *reinterpret_cast<const float4*>(neighrow + k0);
            float4 t1 = *reinterpret_cast<const float4*>(neighrow + k0 + 4);
            float v[8] = {t0.x, t0.y, t0.z, t0.w, t1.x, t1.y, t1.z, t1.w};
            #pragma unroll
            for (int e = 0; e < 8; ++e) {
                short h = f2bf(v[e]);
                ah[e] = h;
                al[e] = f2bf(v[e] - bf2f(h));
            }
        }

        // compact Wp: 64 bf16x8 frags per (ks,nt) block
        const bf16x8* wp = reinterpret_cast<const bf16x8*>(Wp) +
                           (size_t)(ks * 16 + nt0) * 64;
        #pragma unroll
        for (int j = 0; j < NTW; ++j) {
            bf16x8 bh = wp[j * 64 + l];
            acc[j] = __builtin_amdgcn_mfma_f32_16x16x32_bf16(ah, bh, acc[j], 0, 0, 0);
            if (!self_exact)
                acc[j] = __builtin_amdgcn_mfma_f32_16x16x32_bf16(al, bh, acc[j], 0, 0, 0);
        }
    }

    // ---- epilogue: bias (+relu); C/D: col=l&15, row=(l>>4)*4+r ----
    #pragma unroll
    for (int j = 0; j < NTW; ++j) {
        const int col = (nt0 + j) * 16 + lr;
        const float b = bias[col];
        #pragma unroll
        for (int r = 0; r < 4; ++r) {
            const int slot = wrow + lk * 4 + r;
            if (COMPACT && (r0 + slot >= (long)scnt)) continue;
            const long row = COMPACT ? (long)rids[slot] : (r0 + slot);
            float val = acc[j][r] + b;
            if (RELU) val = fmaxf(val, 0.f);
            if constexpr (OUT_BF16)
                ((short*)h_out_v)[row * 256 + col] = f2bf(val);
            else
                ((float*)h_out_v)[row * 256 + col] = val;
        }
    }
}

// ---------------------------------------------------------------------------
// Final layer: M=1024, DIN=256, F=5, DOUT=47, fp32 vector math (tiny).
// ---------------------------------------------------------------------------
__global__ __launch_bounds__(64)
void sage_out(const float* __restrict__ h_in,
              const int*   __restrict__ neigh,
              const float* __restrict__ Wself,
              const float* __restrict__ Wneigh,
              const float* __restrict__ bias,
              float* __restrict__ out)
{
    __shared__ float hs[256], hn[256];
    __shared__ int   nb[5];
    const int r = blockIdx.x, tid = threadIdx.x;

    if (tid < 5) nb[tid] = neigh[r * 5 + tid];
    __syncthreads();

    for (int k = tid; k < 256; k += 64) {
        hs[k] = h_in[(long)r * 256 + k];
        float a = 0.f;
        #pragma unroll
        for (int n = 0; n < 5; ++n) a += h_in[(long)nb[n] * 256 + k];
        hn[k] = a * 0.2f;
    }
    __syncthreads();

    if (tid < 47) {
        float acc = bias[tid];
        for (int k = 0; k < 256; ++k)
            acc += hs[k] * Wself[k * 47 + tid] + hn[k] * Wneigh[k * 47 + tid];
        out[r * 47 + tid] = acc;
    }
}

// ---------------------------------------------------------------------------
extern "C" void kernel_launch(void* const* d_in, const int* in_sizes, int n_in,
                              void* d_out, int out_size, void* d_ws, size_t ws_size,
                              hipStream_t stream)
{
    const float* x   = (const float*)d_in[0];
    const int*   n0  = (const int*)  d_in[1];
    const int*   n1  = (const int*)  d_in[2];
    const int*   n2  = (const int*)  d_in[3];
    const float* Ws0 = (const float*)d_in[4];
    const float* Wn0 = (const float*)d_in[5];
    const float* b0  = (const float*)d_in[6];
    const float* Ws1 = (const float*)d_in[7];
    const float* Wn1 = (const float*)d_in[8];
    const float* b1  = (const float*)d_in[9];
    const float* Ws2 = (const float*)d_in[10];
    const float* Wn2 = (const float*)d_in[11];
    const float* b2  = (const float*)d_in[12];
    float* out = (float*)d_out;

    // workspace layout
    short*    h1   = (short*)d_ws;                         // 67584*256 bf16 = 34.6 MB
    float*    h2   = (float*)(h1 + (size_t)67584 * 256);   //  6144*256 f32  =  6.3 MB
    short*    Wp0  = (short*)(h2 + (size_t)6144 * 256);    // 128*512 bf16 = 128 KB
    short*    Wp1  = Wp0 + (size_t)128 * 512;              // 256*512 bf16 = 256 KB
    unsigned* mask = (unsigned*)(Wp1 + (size_t)256 * 512); // 67584 u32 = 270 KB
    unsigned* list = mask + 67584;                         // 67584 u32 = 270 KB
    unsigned* cnt  = list + 67584;                         // 1 u32

    constexpr int M0 = 67584;

    // demand set for layer 0 (needed rows of h1)
    k_clear  <<<(M0 + 255) / 256, 256, 0, stream>>>(mask, cnt, M0);
    k_mark   <<<(M0 + 255) / 256, 256, 0, stream>>>(n1, mask);
    k_compact<<<(M0 + 255) / 256, 256, 0, stream>>>(mask, list, cnt, M0);

    // weight packs (both layers, one launch)
    pack_w_all<<<384, 64, 0, stream>>>(Ws0, Wn0, Wp0, Ws1, Wn1, Wp1);

    // layer 0: fp32 in, bf16 out; COMPACT demand-driven rows; RB=32, NTW=8
    //          fixed 2112-block grid with count-based early exit
    sage_mfma<128, 15, 32, 8, true,  false, true,  true>
        <<<M0 / 32, 256, 0, stream>>>(x,  n0, Wp0, b0, h1, list, cnt);
    // layer 1: bf16 in, fp32 out; all 6144 rows; RB=16, NTW=4
    sage_mfma<256, 10, 16, 4, false, true,  false, true>
        <<<6144 / 16, 256, 0, stream>>>(h1, n1, Wp1, b1, h2, nullptr, nullptr);
    // layer 2
    sage_out<<<1024, 64, 0, stream>>>(h2, n2, Ws2, Wn2, b2, out);
}

// Round 9
// 130.855 us; speedup vs baseline: 1.4462x; 1.0747x over previous
//
#include <hip/hip_runtime.h>

using bf16x8 = __attribute__((ext_vector_type(8))) short;
using f32x4  = __attribute__((ext_vector_type(4))) float;

// ---- bf16 helpers (RNE) ----------------------------------------------------
__device__ __forceinline__ short f2bf(float x) {
    union { float f; unsigned u; } v; v.f = x;
    unsigned r = v.u + 0x7fffu + ((v.u >> 16) & 1u);
    return (short)(r >> 16);
}
__device__ __forceinline__ float bf2f(short h) {
    union { unsigned u; float f; } v; v.u = ((unsigned)(unsigned short)h) << 16;
    return v.f;
}

// ---------------------------------------------------------------------------
// Pack Wself/Wneigh (fp32, [DIN][256] each) into MFMA B-fragment order,
// bf16 hi only.  blk = ks*16+nt:  Wp[blk*512 + l*8] = frag (8 bf16).
// B-frag: lane l holds B[k = ks*32 + (l>>4)*8 + e][n = nt*16 + (l&15)]
// ---------------------------------------------------------------------------
template<int DIN>
__device__ __forceinline__ void pack_one(int blk, const float* __restrict__ Wself,
                                         const float* __restrict__ Wneigh,
                                         short* __restrict__ Wp, int l)
{
    const int ks  = blk >> 4, nt = blk & 15;
    const int col = nt * 16 + (l & 15);
    const int k0  = ks * 32 + (l >> 4) * 8;

    bf16x8 hi;
    #pragma unroll
    for (int e = 0; e < 8; ++e) {
        int k = k0 + e;
        float w = (k < DIN) ? Wself[k * 256 + col] : Wneigh[(k - DIN) * 256 + col];
        hi[e] = f2bf(w);
    }
    *reinterpret_cast<bf16x8*>(Wp + (size_t)blk * 512 + l * 8) = hi;
}

// ---------------------------------------------------------------------------
// Fused prep (single node): demand-mark + weight-pack.
//   mask must be zeroed beforehand (hipMemsetAsync node). All mask writes
//   store the constant 1u -> idempotent, order-free, deterministic.
//   blocks [0,240):   mask[neigh1[j]] = 1 for j < 61440   (layer-1 gather rows)
//   blocks [240,264): mask[i] = 1 for i < 6144            (layer-1 self rows)
//   blocks [264,360): pack 384 W-fragment units, 4 per block
// ---------------------------------------------------------------------------
__global__ __launch_bounds__(256)
void k_prep(const int* __restrict__ neigh1, unsigned* __restrict__ mask,
            const float* __restrict__ Ws0, const float* __restrict__ Wn0,
            short* __restrict__ Wp0,
            const float* __restrict__ Ws1, const float* __restrict__ Wn1,
            short* __restrict__ Wp1)
{
    const int b = blockIdx.x, tid = threadIdx.x;
    if (b < 240) {
        int j = b * 256 + tid;                 // j < 61440 always
        mask[neigh1[j]] = 1u;
    } else if (b < 264) {
        int i = (b - 240) * 256 + tid;         // i < 6144
        mask[i] = 1u;
    } else {
        int unit = (b - 264) * 4 + (tid >> 6); // 384 units
        int l = tid & 63;
        if (unit < 128) pack_one<128>(unit, Ws0, Wn0, Wp0, l);
        else            pack_one<256>(unit - 128, Ws1, Wn1, Wp1, l);
    }
}

// ---------------------------------------------------------------------------
// Fused SAGE layer, bf16 MFMA (16x16x32) with A-side split correction, DOUT=256.
// Validated phase structure: nb(+need) -> barrier -> gather-mean -> barrier ->
// single k-loop GEMM -> epilogue.
//   MASKED:   per-row demand predication via mask[] (skip gather + store for
//             unneeded rows; their An stays garbage -> row-isolated in MFMA,
//             never stored). Self rows read unconditionally (valid memory).
//   IN_BF16:  input features are bf16 (exact -> 1-term self MFMA)
//   OUT_BF16: write output as bf16
// ---------------------------------------------------------------------------
template<int DIN, int F, int RB, int NTW, bool MASKED, bool IN_BF16, bool OUT_BF16, bool RELU>
__global__ __launch_bounds__(256)
void sage_mfma(const void* __restrict__ h_in_v,
               const int*   __restrict__ neigh,
               const short* __restrict__ Wp,
               const float* __restrict__ bias,
               void* __restrict__ h_out_v,
               const unsigned* __restrict__ mask)
{
    constexpr int KS    = DIN / 16;         // k-steps over Ktot = 2*DIN (32 each)
    constexpr int KSH   = DIN / 32;         // self-half k-steps
    constexpr int LROW  = DIN + 4;
    constexpr int WROWS = RB / 16;
    constexpr int WCOLS = 16 / NTW;
    static_assert(WROWS * WCOLS == 4, "4 waves");
    constexpr float invF = 1.0f / F;

    __shared__ float    An[RB][LROW];       // mean of neighbor rows (fp32)
    __shared__ int      nb[RB * F];
    __shared__ unsigned need[RB];

    const int  tid = threadIdx.x;
    const int  w   = tid >> 6, l = tid & 63;
    const int  lr  = l & 15, lk = l >> 4;
    const long r0  = (long)blockIdx.x * RB;
    const int  wrow = (w % WROWS) * 16;
    const int  nt0  = (w / WROWS) * NTW;

    for (int p = tid; p < RB * F; p += 256)
        nb[p] = neigh[r0 * F + p];
    if constexpr (MASKED) {
        for (int p = tid; p < RB; p += 256)
            need[p] = mask[r0 + p];
    }
    __syncthreads();                        // nb (+need) ready

    if constexpr (!IN_BF16) {
        // ---- gather + mean (fp32 rows) ----
        constexpr int QD = DIN / 4;
        const float* hin = (const float*)h_in_v;
        for (int p = tid; p < RB * QD; p += 256) {
            int m = p / QD, q = p - m * QD;
            if (MASKED && !need[m]) continue;
            float4 a = make_float4(0.f, 0.f, 0.f, 0.f);
            #pragma unroll
            for (int n = 0; n < F; ++n) {
                long idx = nb[m * F + n];
                float4 v = reinterpret_cast<const float4*>(hin + idx * DIN)[q];
                a.x += v.x; a.y += v.y; a.z += v.z; a.w += v.w;
            }
            a.x *= invF; a.y *= invF; a.z *= invF; a.w *= invF;
            *reinterpret_cast<float4*>(&An[m][q * 4]) = a;
        }
    } else {
        // ---- gather + mean (bf16 rows, fp32 accumulate) ----
        constexpr int NQ = DIN / 8;
        const short* hin = (const short*)h_in_v;
        for (int p = tid; p < RB * NQ; p += 256) {
            int m = p / NQ, c = p - m * NQ;
            if (MASKED && !need[m]) continue;
            float a[8] = {0.f,0.f,0.f,0.f,0.f,0.f,0.f,0.f};
            #pragma unroll
            for (int n = 0; n < F; ++n) {
                long idx = nb[m * F + n];
                bf16x8 v = *reinterpret_cast<const bf16x8*>(hin + idx * DIN + c * 8);
                #pragma unroll
                for (int e = 0; e < 8; ++e) a[e] += bf2f(v[e]);
            }
            #pragma unroll
            for (int e = 0; e < 8; ++e) a[e] *= invF;
            *reinterpret_cast<float4*>(&An[m][c * 8])     = make_float4(a[0],a[1],a[2],a[3]);
            *reinterpret_cast<float4*>(&An[m][c * 8 + 4]) = make_float4(a[4],a[5],a[6],a[7]);
        }
    }
    __syncthreads();                        // An ready

    // ---- GEMM: single k-loop, self half from global, neigh half from LDS ----
    const float* selfrowF = (const float*)h_in_v + (r0 + wrow + lr) * DIN;
    const short* selfrowB = (const short*)h_in_v + (r0 + wrow + lr) * DIN;
    const float* neighrow = &An[wrow + lr][0];

    f32x4 acc[NTW];
    #pragma unroll
    for (int j = 0; j < NTW; ++j) acc[j] = f32x4{0.f, 0.f, 0.f, 0.f};

    for (int ks = 0; ks < KS; ++ks) {
        bf16x8 ah, al;
        bool self_exact = false;
        if (ks < KSH) {
            if constexpr (IN_BF16) {
                ah = *reinterpret_cast<const bf16x8*>(selfrowB + ks * 32 + lk * 8);
                self_exact = true;
            } else {
                const int k0 = ks * 32 + lk * 8;
                float4 t0 = *reinterpret_cast<const float4*>(selfrowF + k0);
                float4 t1 = *reinterpret_cast<const float4*>(selfrowF + k0 + 4);
                float v[8] = {t0.x, t0.y, t0.z, t0.w, t1.x, t1.y, t1.z, t1.w};
                #pragma unroll
                for (int e = 0; e < 8; ++e) {
                    short h = f2bf(v[e]);
                    ah[e] = h;
                    al[e] = f2bf(v[e] - bf2f(h));
                }
            }
        } else {
            const int k0 = (ks - KSH) * 32 + lk * 8;
            float4 t0 = *reinterpret_cast<const float4*>(neighrow + k0);
            float4 t1 = *reinterpret_cast<const float4*>(neighrow + k0 + 4);
            float v[8] = {t0.x, t0.y, t0.z, t0.w, t1.x, t1.y, t1.z, t1.w};
            #pragma unroll
            for (int e = 0; e < 8; ++e) {
                short h = f2bf(v[e]);
                ah[e] = h;
                al[e] = f2bf(v[e] - bf2f(h));
            }
        }

        // compact Wp: 64 bf16x8 frags per (ks,nt) block
        const bf16x8* wp = reinterpret_cast<const bf16x8*>(Wp) +
                           (size_t)(ks * 16 + nt0) * 64;
        #pragma unroll
        for (int j = 0; j < NTW; ++j) {
            bf16x8 bh = wp[j * 64 + l];
            acc[j] = __builtin_amdgcn_mfma_f32_16x16x32_bf16(ah, bh, acc[j], 0, 0, 0);
            if (!self_exact)
                acc[j] = __builtin_amdgcn_mfma_f32_16x16x32_bf16(al, bh, acc[j], 0, 0, 0);
        }
    }

    // ---- epilogue: bias (+relu); C/D: col=l&15, row=(l>>4)*4+r ----
    #pragma unroll
    for (int j = 0; j < NTW; ++j) {
        const int col = (nt0 + j) * 16 + lr;
        const float b = bias[col];
        #pragma unroll
        for (int r = 0; r < 4; ++r) {
            const int slot = wrow + lk * 4 + r;
            if (MASKED && !need[slot]) continue;
            const long row = r0 + slot;
            float val = acc[j][r] + b;
            if (RELU) val = fmaxf(val, 0.f);
            if constexpr (OUT_BF16)
                ((short*)h_out_v)[row * 256 + col] = f2bf(val);
            else
                ((float*)h_out_v)[row * 256 + col] = val;
        }
    }
}

// ---------------------------------------------------------------------------
// Final layer: M=1024, DIN=256, F=5, DOUT=47, fp32 vector math.
// 4-way accumulator split for ILP (fp32 chain is otherwise serial).
// ---------------------------------------------------------------------------
__global__ __launch_bounds__(64)
void sage_out(const float* __restrict__ h_in,
              const int*   __restrict__ neigh,
              const float* __restrict__ Wself,
              const float* __restrict__ Wneigh,
              const float* __restrict__ bias,
              float* __restrict__ out)
{
    __shared__ float hs[256], hn[256];
    __shared__ int   nb[5];
    const int r = blockIdx.x, tid = threadIdx.x;

    if (tid < 5) nb[tid] = neigh[r * 5 + tid];
    __syncthreads();

    for (int k = tid; k < 256; k += 64) {
        hs[k] = h_in[(long)r * 256 + k];
        float a = 0.f;
        #pragma unroll
        for (int n = 0; n < 5; ++n) a += h_in[(long)nb[n] * 256 + k];
        hn[k] = a * 0.2f;
    }
    __syncthreads();

    if (tid < 47) {
        float a0 = 0.f, a1 = 0.f, a2 = 0.f, a3 = 0.f;
        #pragma unroll 4
        for (int k = 0; k < 256; k += 4) {
            a0 += hs[k    ] * Wself[(k    ) * 47 + tid] + hn[k    ] * Wneigh[(k    ) * 47 + tid];
            a1 += hs[k + 1] * Wself[(k + 1) * 47 + tid] + hn[k + 1] * Wneigh[(k + 1) * 47 + tid];
            a2 += hs[k + 2] * Wself[(k + 2) * 47 + tid] + hn[k + 2] * Wneigh[(k + 2) * 47 + tid];
            a3 += hs[k + 3] * Wself[(k + 3) * 47 + tid] + hn[k + 3] * Wneigh[(k + 3) * 47 + tid];
        }
        out[r * 47 + tid] = bias[tid] + ((a0 + a1) + (a2 + a3));
    }
}

// ---------------------------------------------------------------------------
extern "C" void kernel_launch(void* const* d_in, const int* in_sizes, int n_in,
                              void* d_out, int out_size, void* d_ws, size_t ws_size,
                              hipStream_t stream)
{
    const float* x   = (const float*)d_in[0];
    const int*   n0  = (const int*)  d_in[1];
    const int*   n1  = (const int*)  d_in[2];
    const int*   n2  = (const int*)  d_in[3];
    const float* Ws0 = (const float*)d_in[4];
    const float* Wn0 = (const float*)d_in[5];
    const float* b0  = (const float*)d_in[6];
    const float* Ws1 = (const float*)d_in[7];
    const float* Wn1 = (const float*)d_in[8];
    const float* b1  = (const float*)d_in[9];
    const float* Ws2 = (const float*)d_in[10];
    const float* Wn2 = (const float*)d_in[11];
    const float* b2  = (const float*)d_in[12];
    float* out = (float*)d_out;

    // workspace layout
    short*    h1   = (short*)d_ws;                         // 67584*256 bf16 = 34.6 MB
    float*    h2   = (float*)(h1 + (size_t)67584 * 256);   //  6144*256 f32  =  6.3 MB
    short*    Wp0  = (short*)(h2 + (size_t)6144 * 256);    // 128*512 bf16 = 128 KB
    short*    Wp1  = Wp0 + (size_t)128 * 512;              // 256*512 bf16 = 256 KB
    unsigned* mask = (unsigned*)(Wp1 + (size_t)256 * 512); // 67584 u32 = 270 KB

    constexpr int M0 = 67584;

    // node 1: zero the demand mask (memset node — cheap, capture-legal)
    hipMemsetAsync(mask, 0, (size_t)M0 * sizeof(unsigned), stream);

    // node 2: fused prep — demand marks (idempotent 1u stores) + weight packs
    k_prep<<<360, 256, 0, stream>>>(n1, mask, Ws0, Wn0, Wp0, Ws1, Wn1, Wp1);

    // node 3: layer 0 — fp32 in, bf16 out; MASKED per-row demand predication
    sage_mfma<128, 15, 32, 8, true,  false, true,  true>
        <<<M0 / 32, 256, 0, stream>>>(x,  n0, Wp0, b0, h1, mask);

    // node 4: layer 1 — bf16 in, fp32 out; all 6144 rows
    sage_mfma<256, 10, 16, 4, false, true,  false, true>
        <<<6144 / 16, 256, 0, stream>>>(h1, n1, Wp1, b1, h2, nullptr);

    // node 5: layer 2
    sage_out<<<1024, 64, 0, stream>>>(h2, n2, Ws2, Wn2, b2, out);
}

// Round 10
// 128.326 us; speedup vs baseline: 1.4747x; 1.0197x over previous
//
#include <hip/hip_runtime.h>

using bf16x8 = __attribute__((ext_vector_type(8))) short;
using f32x4  = __attribute__((ext_vector_type(4))) float;

// ---- bf16 helpers (RNE) ----------------------------------------------------
__device__ __forceinline__ short f2bf(float x) {
    union { float f; unsigned u; } v; v.f = x;
    unsigned r = v.u + 0x7fffu + ((v.u >> 16) & 1u);
    return (short)(r >> 16);
}
__device__ __forceinline__ float bf2f(short h) {
    union { unsigned u; float f; } v; v.u = ((unsigned)(unsigned short)h) << 16;
    return v.f;
}

// ---------------------------------------------------------------------------
// Pack Wself/Wneigh (fp32, [DIN][256] each) into MFMA B-fragment order,
// bf16 hi only.  blk = ks*16+nt:  Wp[blk*512 + l*8] = frag (8 bf16).
// B-frag: lane l holds B[k = ks*32 + (l>>4)*8 + e][n = nt*16 + (l&15)]
// ---------------------------------------------------------------------------
template<int DIN>
__device__ __forceinline__ void pack_one(int blk, const float* __restrict__ Wself,
                                         const float* __restrict__ Wneigh,
                                         short* __restrict__ Wp, int l)
{
    const int ks  = blk >> 4, nt = blk & 15;
    const int col = nt * 16 + (l & 15);
    const int k0  = ks * 32 + (l >> 4) * 8;

    bf16x8 hi;
    #pragma unroll
    for (int e = 0; e < 8; ++e) {
        int k = k0 + e;
        float w = (k < DIN) ? Wself[k * 256 + col] : Wneigh[(k - DIN) * 256 + col];
        hi[e] = f2bf(w);
    }
    *reinterpret_cast<bf16x8*>(Wp + (size_t)blk * 512 + l * 8) = hi;
}

// ---------------------------------------------------------------------------
// Fused prep (single node, NO prior clear needed): demand-mark + weight-pack.
// Mark-only mask semantics: mask[i]==1 => compute row i. k_prep writes 1 to
// every NEEDED entry each call, so needed rows are always marked before the
// layer kernels read them. Unneeded entries hold whatever the buffer holds
// (0xAA poison / garbage); a spurious 1 only computes a correct-but-unused
// row (benign). Marked set is input-determined => deterministic output.
//   blocks [0,240):    mask0[neigh1[j]] = 1, j < 61440  (h1 rows L1 gathers)
//   blocks [240,264):  mask0[i] = 1, i < 6144           (h1 rows L1 self-reads)
//   blocks [264,284):  mask1[neigh2[j]] = 1, j < 5120   (h2 rows L2 gathers)
//   blocks [284,288):  mask1[i] = 1, i < 1024           (h2 rows L2 self-reads)
//   blocks [288,384):  pack 384 W-fragment units, 4 per block
// ---------------------------------------------------------------------------
__global__ __launch_bounds__(256)
void k_prep(const int* __restrict__ neigh1, const int* __restrict__ neigh2,
            unsigned char* __restrict__ mask0, unsigned char* __restrict__ mask1,
            const float* __restrict__ Ws0, const float* __restrict__ Wn0,
            short* __restrict__ Wp0,
            const float* __restrict__ Ws1, const float* __restrict__ Wn1,
            short* __restrict__ Wp1)
{
    const int b = blockIdx.x, tid = threadIdx.x;
    if (b < 240) {
        int j = b * 256 + tid;                 // j < 61440 exactly
        mask0[neigh1[j]] = 1;
    } else if (b < 264) {
        int i = (b - 240) * 256 + tid;         // i < 6144 exactly
        mask0[i] = 1;
    } else if (b < 284) {
        int j = (b - 264) * 256 + tid;         // j < 5120 exactly
        mask1[neigh2[j]] = 1;
    } else if (b < 288) {
        int i = (b - 284) * 256 + tid;         // i < 1024 exactly
        mask1[i] = 1;
    } else {
        int unit = (b - 288) * 4 + (tid >> 6); // 384 units
        int l = tid & 63;
        if (unit < 128) pack_one<128>(unit, Ws0, Wn0, Wp0, l);
        else            pack_one<256>(unit - 128, Ws1, Wn1, Wp1, l);
    }
}

// ---------------------------------------------------------------------------
// Fused SAGE layer, bf16 MFMA (16x16x32) with A-side split correction, DOUT=256.
// Validated phase structure: nb(+need) -> barrier -> gather-mean -> barrier ->
// single k-loop GEMM -> epilogue.
//   MASKED:   per-row demand predication via byte mask (skip gather + store
//             for rows with mask!=1; their An stays garbage -> row-isolated
//             in MFMA, never stored). Self rows read unconditionally.
//   IN_BF16:  input features are bf16 (exact -> 1-term self MFMA)
//   OUT_BF16: write output as bf16
// ---------------------------------------------------------------------------
template<int DIN, int F, int RB, int NTW, bool MASKED, bool IN_BF16, bool OUT_BF16, bool RELU>
__global__ __launch_bounds__(256)
void sage_mfma(const void* __restrict__ h_in_v,
               const int*   __restrict__ neigh,
               const short* __restrict__ Wp,
               const float* __restrict__ bias,
               void* __restrict__ h_out_v,
               const unsigned char* __restrict__ mask)
{
    constexpr int KS    = DIN / 16;         // k-steps over Ktot = 2*DIN (32 each)
    constexpr int KSH   = DIN / 32;         // self-half k-steps
    constexpr int LROW  = DIN + 4;
    constexpr int WROWS = RB / 16;
    constexpr int WCOLS = 16 / NTW;
    static_assert(WROWS * WCOLS == 4, "4 waves");
    constexpr float invF = 1.0f / F;

    __shared__ float         An[RB][LROW];  // mean of neighbor rows (fp32)
    __shared__ int           nb[RB * F];
    __shared__ unsigned char need[RB];

    const int  tid = threadIdx.x;
    const int  w   = tid >> 6, l = tid & 63;
    const int  lr  = l & 15, lk = l >> 4;
    const long r0  = (long)blockIdx.x * RB;
    const int  wrow = (w % WROWS) * 16;
    const int  nt0  = (w / WROWS) * NTW;

    for (int p = tid; p < RB * F; p += 256)
        nb[p] = neigh[r0 * F + p];
    if constexpr (MASKED) {
        for (int p = tid; p < RB; p += 256)
            need[p] = mask[r0 + p];
    }
    __syncthreads();                        // nb (+need) ready

    if constexpr (!IN_BF16) {
        // ---- gather + mean (fp32 rows) ----
        constexpr int QD = DIN / 4;
        const float* hin = (const float*)h_in_v;
        for (int p = tid; p < RB * QD; p += 256) {
            int m = p / QD, q = p - m * QD;
            if (MASKED && need[m] != 1) continue;
            float4 a = make_float4(0.f, 0.f, 0.f, 0.f);
            #pragma unroll
            for (int n = 0; n < F; ++n) {
                long idx = nb[m * F + n];
                float4 v = reinterpret_cast<const float4*>(hin + idx * DIN)[q];
                a.x += v.x; a.y += v.y; a.z += v.z; a.w += v.w;
            }
            a.x *= invF; a.y *= invF; a.z *= invF; a.w *= invF;
            *reinterpret_cast<float4*>(&An[m][q * 4]) = a;
        }
    } else {
        // ---- gather + mean (bf16 rows, fp32 accumulate) ----
        constexpr int NQ = DIN / 8;
        const short* hin = (const short*)h_in_v;
        for (int p = tid; p < RB * NQ; p += 256) {
            int m = p / NQ, c = p - m * NQ;
            if (MASKED && need[m] != 1) continue;
            float a[8] = {0.f,0.f,0.f,0.f,0.f,0.f,0.f,0.f};
            #pragma unroll
            for (int n = 0; n < F; ++n) {
                long idx = nb[m * F + n];
                bf16x8 v = *reinterpret_cast<const bf16x8*>(hin + idx * DIN + c * 8);
                #pragma unroll
                for (int e = 0; e < 8; ++e) a[e] += bf2f(v[e]);
            }
            #pragma unroll
            for (int e = 0; e < 8; ++e) a[e] *= invF;
            *reinterpret_cast<float4*>(&An[m][c * 8])     = make_float4(a[0],a[1],a[2],a[3]);
            *reinterpret_cast<float4*>(&An[m][c * 8 + 4]) = make_float4(a[4],a[5],a[6],a[7]);
        }
    }
    __syncthreads();                        // An ready

    // ---- GEMM: single k-loop, self half from global, neigh half from LDS ----
    const float* selfrowF = (const float*)h_in_v + (r0 + wrow + lr) * DIN;
    const short* selfrowB = (const short*)h_in_v + (r0 + wrow + lr) * DIN;
    const float* neighrow = &An[wrow + lr][0];

    f32x4 acc[NTW];
    #pragma unroll
    for (int j = 0; j < NTW; ++j) acc[j] = f32x4{0.f, 0.f, 0.f, 0.f};

    for (int ks = 0; ks < KS; ++ks) {
        bf16x8 ah, al;
        bool self_exact = false;
        if (ks < KSH) {
            if constexpr (IN_BF16) {
                ah = *reinterpret_cast<const bf16x8*>(selfrowB + ks * 32 + lk * 8);
                self_exact = true;
            } else {
                const int k0 = ks * 32 + lk * 8;
                float4 t0 = *reinterpret_cast<const float4*>(selfrowF + k0);
                float4 t1 = *reinterpret_cast<const float4*>(selfrowF + k0 + 4);
                float v[8] = {t0.x, t0.y, t0.z, t0.w, t1.x, t1.y, t1.z, t1.w};
                #pragma unroll
                for (int e = 0; e < 8; ++e) {
                    short h = f2bf(v[e]);
                    ah[e] = h;
                    al[e] = f2bf(v[e] - bf2f(h));
                }
            }
        } else {
            const int k0 = (ks - KSH) * 32 + lk * 8;
            float4 t0 = *reinterpret_cast<const float4*>(neighrow + k0);
            float4 t1 = *reinterpret_cast<const float4*>(neighrow + k0 + 4);
            float v[8] = {t0.x, t0.y, t0.z, t0.w, t1.x, t1.y, t1.z, t1.w};
            #pragma unroll
            for (int e = 0; e < 8; ++e) {
                short h = f2bf(v[e]);
                ah[e] = h;
                al[e] = f2bf(v[e] - bf2f(h));
            }
        }

        // compact Wp: 64 bf16x8 frags per (ks,nt) block
        const bf16x8* wp = reinterpret_cast<const bf16x8*>(Wp) +
                           (size_t)(ks * 16 + nt0) * 64;
        #pragma unroll
        for (int j = 0; j < NTW; ++j) {
            bf16x8 bh = wp[j * 64 + l];
            acc[j] = __builtin_amdgcn_mfma_f32_16x16x32_bf16(ah, bh, acc[j], 0, 0, 0);
            if (!self_exact)
                acc[j] = __builtin_amdgcn_mfma_f32_16x16x32_bf16(al, bh, acc[j], 0, 0, 0);
        }
    }

    // ---- epilogue: bias (+relu); C/D: col=l&15, row=(l>>4)*4+r ----
    #pragma unroll
    for (int j = 0; j < NTW; ++j) {
        const int col = (nt0 + j) * 16 + lr;
        const float b = bias[col];
        #pragma unroll
        for (int r = 0; r < 4; ++r) {
            const int slot = wrow + lk * 4 + r;
            if (MASKED && need[slot] != 1) continue;
            const long row = r0 + slot;
            float val = acc[j][r] + b;
            if (RELU) val = fmaxf(val, 0.f);
            if constexpr (OUT_BF16)
                ((short*)h_out_v)[row * 256 + col] = f2bf(val);
            else
                ((float*)h_out_v)[row * 256 + col] = val;
        }
    }
}

// ---------------------------------------------------------------------------
// Final layer: M=1024, DIN=256, F=5, DOUT=47, fp32 vector math.
// 4-way accumulator split for ILP (fp32 chain is otherwise serial).
// ---------------------------------------------------------------------------
__global__ __launch_bounds__(64)
void sage_out(const float* __restrict__ h_in,
              const int*   __restrict__ neigh,
              const float* __restrict__ Wself,
              const float* __restrict__ Wneigh,
              const float* __restrict__ bias,
              float* __restrict__ out)
{
    __shared__ float hs[256], hn[256];
    __shared__ int   nb[5];
    const int r = blockIdx.x, tid = threadIdx.x;

    if (tid < 5) nb[tid] = neigh[r * 5 + tid];
    __syncthreads();

    for (int k = tid; k < 256; k += 64) {
        hs[k] = h_in[(long)r * 256 + k];
        float a = 0.f;
        #pragma unroll
        for (int n = 0; n < 5; ++n) a += h_in[(long)nb[n] * 256 + k];
        hn[k] = a * 0.2f;
    }
    __syncthreads();

    if (tid < 47) {
        float a0 = 0.f, a1 = 0.f, a2 = 0.f, a3 = 0.f;
        #pragma unroll 4
        for (int k = 0; k < 256; k += 4) {
            a0 += hs[k    ] * Wself[(k    ) * 47 + tid] + hn[k    ] * Wneigh[(k    ) * 47 + tid];
            a1 += hs[k + 1] * Wself[(k + 1) * 47 + tid] + hn[k + 1] * Wneigh[(k + 1) * 47 + tid];
            a2 += hs[k + 2] * Wself[(k + 2) * 47 + tid] + hn[k + 2] * Wneigh[(k + 2) * 47 + tid];
            a3 += hs[k + 3] * Wself[(k + 3) * 47 + tid] + hn[k + 3] * Wneigh[(k + 3) * 47 + tid];
        }
        out[r * 47 + tid] = bias[tid] + ((a0 + a1) + (a2 + a3));
    }
}

// ---------------------------------------------------------------------------
extern "C" void kernel_launch(void* const* d_in, const int* in_sizes, int n_in,
                              void* d_out, int out_size, void* d_ws, size_t ws_size,
                              hipStream_t stream)
{
    const float* x   = (const float*)d_in[0];
    const int*   n0  = (const int*)  d_in[1];
    const int*   n1  = (const int*)  d_in[2];
    const int*   n2  = (const int*)  d_in[3];
    const float* Ws0 = (const float*)d_in[4];
    const float* Wn0 = (const float*)d_in[5];
    const float* b0  = (const float*)d_in[6];
    const float* Ws1 = (const float*)d_in[7];
    const float* Wn1 = (const float*)d_in[8];
    const float* b1  = (const float*)d_in[9];
    const float* Ws2 = (const float*)d_in[10];
    const float* Wn2 = (const float*)d_in[11];
    const float* b2  = (const float*)d_in[12];
    float* out = (float*)d_out;

    // workspace layout
    short*         h1    = (short*)d_ws;                          // 67584*256 bf16 = 34.6 MB
    float*         h2    = (float*)(h1 + (size_t)67584 * 256);    //  6144*256 f32  =  6.3 MB
    short*         Wp0   = (short*)(h2 + (size_t)6144 * 256);     // 128*512 bf16 = 128 KB
    short*         Wp1   = Wp0 + (size_t)128 * 512;               // 256*512 bf16 = 256 KB
    unsigned char* mask0 = (unsigned char*)(Wp1 + (size_t)256 * 512); // 67584 B
    unsigned char* mask1 = mask0 + 67584;                         // 6144 B

    constexpr int M0 = 67584;

    // node 1: fused prep — demand marks for h1 & h2 (mark-only, no clear
    //         needed: mask==1 means compute; spurious 1s are benign) + W packs
    k_prep<<<384, 256, 0, stream>>>(n1, n2, mask0, mask1,
                                    Ws0, Wn0, Wp0, Ws1, Wn1, Wp1);

    // node 2: layer 0 — fp32 in, bf16 out; demand-masked rows
    sage_mfma<128, 15, 32, 8, true,  false, true,  true>
        <<<M0 / 32, 256, 0, stream>>>(x,  n0, Wp0, b0, h1, mask0);

    // node 3: layer 1 — bf16 in, fp32 out; demand-masked rows
    sage_mfma<256, 10, 16, 4, true,  true,  false, true>
        <<<6144 / 16, 256, 0, stream>>>(h1, n1, Wp1, b1, h2, mask1);

    // node 4: layer 2
    sage_out<<<1024, 64, 0, stream>>>(h2, n2, Ws2, Wn2, b2, out);
}

// Round 11
// 128.038 us; speedup vs baseline: 1.4780x; 1.0023x over previous
//
#include <hip/hip_runtime.h>

using bf16x8 = __attribute__((ext_vector_type(8))) short;
using f32x4  = __attribute__((ext_vector_type(4))) float;

// ---- bf16 helpers (RNE) ----------------------------------------------------
__device__ __forceinline__ short f2bf(float x) {
    union { float f; unsigned u; } v; v.f = x;
    unsigned r = v.u + 0x7fffu + ((v.u >> 16) & 1u);
    return (short)(r >> 16);
}
__device__ __forceinline__ float bf2f(short h) {
    union { unsigned u; float f; } v; v.u = ((unsigned)(unsigned short)h) << 16;
    return v.f;
}

// ---------------------------------------------------------------------------
// Pack Wself/Wneigh (fp32, [DIN][256] each) into MFMA B-fragment order,
// bf16 hi only.  blk = ks*16+nt:  Wp[blk*512 + l*8] = frag (8 bf16).
// B-frag: lane l holds B[k = ks*32 + (l>>4)*8 + e][n = nt*16 + (l&15)]
// ---------------------------------------------------------------------------
template<int DIN>
__device__ __forceinline__ void pack_one(int blk, const float* __restrict__ Wself,
                                         const float* __restrict__ Wneigh,
                                         short* __restrict__ Wp, int l)
{
    const int ks  = blk >> 4, nt = blk & 15;
    const int col = nt * 16 + (l & 15);
    const int k0  = ks * 32 + (l >> 4) * 8;

    bf16x8 hi;
    #pragma unroll
    for (int e = 0; e < 8; ++e) {
        int k = k0 + e;
        float w = (k < DIN) ? Wself[k * 256 + col] : Wneigh[(k - DIN) * 256 + col];
        hi[e] = f2bf(w);
    }
    *reinterpret_cast<bf16x8*>(Wp + (size_t)blk * 512 + l * 8) = hi;
}

// ---------------------------------------------------------------------------
// Fused prep (single node, NO prior clear needed): demand-mark + weight-pack.
// Mark-only mask semantics: mask[i]==1 => compute row i. k_prep writes 1 to
// every NEEDED entry each call, so needed rows are always marked before the
// layer kernels read them. Unneeded entries hold whatever the buffer holds
// (0xAA poison / garbage); a spurious 1 only computes a correct-but-unused
// row (benign). Marked set is input-determined => deterministic output.
// ---------------------------------------------------------------------------
__global__ __launch_bounds__(256)
void k_prep(const int* __restrict__ neigh1, const int* __restrict__ neigh2,
            unsigned char* __restrict__ mask0, unsigned char* __restrict__ mask1,
            const float* __restrict__ Ws0, const float* __restrict__ Wn0,
            short* __restrict__ Wp0,
            const float* __restrict__ Ws1, const float* __restrict__ Wn1,
            short* __restrict__ Wp1)
{
    const int b = blockIdx.x, tid = threadIdx.x;
    if (b < 240) {
        int j = b * 256 + tid;                 // j < 61440 exactly
        mask0[neigh1[j]] = 1;
    } else if (b < 264) {
        int i = (b - 240) * 256 + tid;         // i < 6144 exactly
        mask0[i] = 1;
    } else if (b < 284) {
        int j = (b - 264) * 256 + tid;         // j < 5120 exactly
        mask1[neigh2[j]] = 1;
    } else if (b < 288) {
        int i = (b - 284) * 256 + tid;         // i < 1024 exactly
        mask1[i] = 1;
    } else {
        int unit = (b - 288) * 4 + (tid >> 6); // 384 units
        int l = tid & 63;
        if (unit < 128) pack_one<128>(unit, Ws0, Wn0, Wp0, l);
        else            pack_one<256>(unit - 128, Ws1, Wn1, Wp1, l);
    }
}

// ---------------------------------------------------------------------------
// Fused SAGE layer, bf16 MFMA (16x16x32) with A-side split correction, DOUT=256.
// Validated phase structure: nb(+need) -> barrier -> gather-mean -> barrier ->
// single k-loop GEMM -> epilogue.
// R11: gather neighbor loop capped at unroll 5 (fewer live VGPRs) and
// __launch_bounds__(256, 6) to raise occupancy to ~6 waves/SIMD; the lost
// per-lane MLP is recovered by the extra resident waves. Neighbor summation
// ORDER is unchanged (sequential n) -> bit-identical results.
// ---------------------------------------------------------------------------
template<int DIN, int F, int RB, int NTW, bool MASKED, bool IN_BF16, bool OUT_BF16, bool RELU>
__global__ __launch_bounds__(256, 6)
void sage_mfma(const void* __restrict__ h_in_v,
               const int*   __restrict__ neigh,
               const short* __restrict__ Wp,
               const float* __restrict__ bias,
               void* __restrict__ h_out_v,
               const unsigned char* __restrict__ mask)
{
    constexpr int KS    = DIN / 16;         // k-steps over Ktot = 2*DIN (32 each)
    constexpr int KSH   = DIN / 32;         // self-half k-steps
    constexpr int LROW  = DIN + 4;
    constexpr int WROWS = RB / 16;
    constexpr int WCOLS = 16 / NTW;
    static_assert(WROWS * WCOLS == 4, "4 waves");
    constexpr float invF = 1.0f / F;

    __shared__ float         An[RB][LROW];  // mean of neighbor rows (fp32)
    __shared__ int           nb[RB * F];
    __shared__ unsigned char need[RB];

    const int  tid = threadIdx.x;
    const int  w   = tid >> 6, l = tid & 63;
    const int  lr  = l & 15, lk = l >> 4;
    const long r0  = (long)blockIdx.x * RB;
    const int  wrow = (w % WROWS) * 16;
    const int  nt0  = (w / WROWS) * NTW;

    for (int p = tid; p < RB * F; p += 256)
        nb[p] = neigh[r0 * F + p];
    if constexpr (MASKED) {
        for (int p = tid; p < RB; p += 256)
            need[p] = mask[r0 + p];
    }
    __syncthreads();                        // nb (+need) ready

    if constexpr (!IN_BF16) {
        // ---- gather + mean (fp32 rows) ----
        constexpr int QD = DIN / 4;
        const float* hin = (const float*)h_in_v;
        for (int p = tid; p < RB * QD; p += 256) {
            int m = p / QD, q = p - m * QD;
            if (MASKED && need[m] != 1) continue;
            float4 a = make_float4(0.f, 0.f, 0.f, 0.f);
            #pragma unroll 5
            for (int n = 0; n < F; ++n) {
                long idx = nb[m * F + n];
                float4 v = reinterpret_cast<const float4*>(hin + idx * DIN)[q];
                a.x += v.x; a.y += v.y; a.z += v.z; a.w += v.w;
            }
            a.x *= invF; a.y *= invF; a.z *= invF; a.w *= invF;
            *reinterpret_cast<float4*>(&An[m][q * 4]) = a;
        }
    } else {
        // ---- gather + mean (bf16 rows, fp32 accumulate) ----
        constexpr int NQ = DIN / 8;
        const short* hin = (const short*)h_in_v;
        for (int p = tid; p < RB * NQ; p += 256) {
            int m = p / NQ, c = p - m * NQ;
            if (MASKED && need[m] != 1) continue;
            float a[8] = {0.f,0.f,0.f,0.f,0.f,0.f,0.f,0.f};
            #pragma unroll 5
            for (int n = 0; n < F; ++n) {
                long idx = nb[m * F + n];
                bf16x8 v = *reinterpret_cast<const bf16x8*>(hin + idx * DIN + c * 8);
                #pragma unroll
                for (int e = 0; e < 8; ++e) a[e] += bf2f(v[e]);
            }
            #pragma unroll
            for (int e = 0; e < 8; ++e) a[e] *= invF;
            *reinterpret_cast<float4*>(&An[m][c * 8])     = make_float4(a[0],a[1],a[2],a[3]);
            *reinterpret_cast<float4*>(&An[m][c * 8 + 4]) = make_float4(a[4],a[5],a[6],a[7]);
        }
    }
    __syncthreads();                        // An ready

    // ---- GEMM: single k-loop, self half from global, neigh half from LDS ----
    const float* selfrowF = (const float*)h_in_v + (r0 + wrow + lr) * DIN;
    const short* selfrowB = (const short*)h_in_v + (r0 + wrow + lr) * DIN;
    const float* neighrow = &An[wrow + lr][0];

    f32x4 acc[NTW];
    #pragma unroll
    for (int j = 0; j < NTW; ++j) acc[j] = f32x4{0.f, 0.f, 0.f, 0.f};

    for (int ks = 0; ks < KS; ++ks) {
        bf16x8 ah, al;
        bool self_exact = false;
        if (ks < KSH) {
            if constexpr (IN_BF16) {
                ah = *reinterpret_cast<const bf16x8*>(selfrowB + ks * 32 + lk * 8);
                self_exact = true;
            } else {
                const int k0 = ks * 32 + lk * 8;
                float4 t0 = *reinterpret_cast<const float4*>(selfrowF + k0);
                float4 t1 = *reinterpret_cast<const float4*>(selfrowF + k0 + 4);
                float v[8] = {t0.x, t0.y, t0.z, t0.w, t1.x, t1.y, t1.z, t1.w};
                #pragma unroll
                for (int e = 0; e < 8; ++e) {
                    short h = f2bf(v[e]);
                    ah[e] = h;
                    al[e] = f2bf(v[e] - bf2f(h));
                }
            }
        } else {
            const int k0 = (ks - KSH) * 32 + lk * 8;
            float4 t0 = *reinterpret_cast<const float4*>(neighrow + k0);
            float4 t1 = *reinterpret_cast<const float4*>(neighrow + k0 + 4);
            float v[8] = {t0.x, t0.y, t0.z, t0.w, t1.x, t1.y, t1.z, t1.w};
            #pragma unroll
            for (int e = 0; e < 8; ++e) {
                short h = f2bf(v[e]);
                ah[e] = h;
                al[e] = f2bf(v[e] - bf2f(h));
            }
        }

        // compact Wp: 64 bf16x8 frags per (ks,nt) block
        const bf16x8* wp = reinterpret_cast<const bf16x8*>(Wp) +
                           (size_t)(ks * 16 + nt0) * 64;
        #pragma unroll
        for (int j = 0; j < NTW; ++j) {
            bf16x8 bh = wp[j * 64 + l];
            acc[j] = __builtin_amdgcn_mfma_f32_16x16x32_bf16(ah, bh, acc[j], 0, 0, 0);
            if (!self_exact)
                acc[j] = __builtin_amdgcn_mfma_f32_16x16x32_bf16(al, bh, acc[j], 0, 0, 0);
        }
    }

    // ---- epilogue: bias (+relu); C/D: col=l&15, row=(l>>4)*4+r ----
    #pragma unroll
    for (int j = 0; j < NTW; ++j) {
        const int col = (nt0 + j) * 16 + lr;
        const float b = bias[col];
        #pragma unroll
        for (int r = 0; r < 4; ++r) {
            const int slot = wrow + lk * 4 + r;
            if (MASKED && need[slot] != 1) continue;
            const long row = r0 + slot;
            float val = acc[j][r] + b;
            if (RELU) val = fmaxf(val, 0.f);
            if constexpr (OUT_BF16)
                ((short*)h_out_v)[row * 256 + col] = f2bf(val);
            else
                ((float*)h_out_v)[row * 256 + col] = val;
        }
    }
}

// ---------------------------------------------------------------------------
// Final layer: M=1024, DIN=256, F=5, DOUT=47, fp32 vector math.
// 4-way accumulator split for ILP (fp32 chain is otherwise serial).
// ---------------------------------------------------------------------------
__global__ __launch_bounds__(64)
void sage_out(const float* __restrict__ h_in,
              const int*   __restrict__ neigh,
              const float* __restrict__ Wself,
              const float* __restrict__ Wneigh,
              const float* __restrict__ bias,
              float* __restrict__ out)
{
    __shared__ float hs[256], hn[256];
    __shared__ int   nb[5];
    const int r = blockIdx.x, tid = threadIdx.x;

    if (tid < 5) nb[tid] = neigh[r * 5 + tid];
    __syncthreads();

    for (int k = tid; k < 256; k += 64) {
        hs[k] = h_in[(long)r * 256 + k];
        float a = 0.f;
        #pragma unroll
        for (int n = 0; n < 5; ++n) a += h_in[(long)nb[n] * 256 + k];
        hn[k] = a * 0.2f;
    }
    __syncthreads();

    if (tid < 47) {
        float a0 = 0.f, a1 = 0.f, a2 = 0.f, a3 = 0.f;
        #pragma unroll 4
        for (int k = 0; k < 256; k += 4) {
            a0 += hs[k    ] * Wself[(k    ) * 47 + tid] + hn[k    ] * Wneigh[(k    ) * 47 + tid];
            a1 += hs[k + 1] * Wself[(k + 1) * 47 + tid] + hn[k + 1] * Wneigh[(k + 1) * 47 + tid];
            a2 += hs[k + 2] * Wself[(k + 2) * 47 + tid] + hn[k + 2] * Wneigh[(k + 2) * 47 + tid];
            a3 += hs[k + 3] * Wself[(k + 3) * 47 + tid] + hn[k + 3] * Wneigh[(k + 3) * 47 + tid];
        }
        out[r * 47 + tid] = bias[tid] + ((a0 + a1) + (a2 + a3));
    }
}

// ---------------------------------------------------------------------------
extern "C" void kernel_launch(void* const* d_in, const int* in_sizes, int n_in,
                              void* d_out, int out_size, void* d_ws, size_t ws_size,
                              hipStream_t stream)
{
    const float* x   = (const float*)d_in[0];
    const int*   n0  = (const int*)  d_in[1];
    const int*   n1  = (const int*)  d_in[2];
    const int*   n2  = (const int*)  d_in[3];
    const float* Ws0 = (const float*)d_in[4];
    const float* Wn0 = (const float*)d_in[5];
    const float* b0  = (const float*)d_in[6];
    const float* Ws1 = (const float*)d_in[7];
    const float* Wn1 = (const float*)d_in[8];
    const float* b1  = (const float*)d_in[9];
    const float* Ws2 = (const float*)d_in[10];
    const float* Wn2 = (const float*)d_in[11];
    const float* b2  = (const float*)d_in[12];
    float* out = (float*)d_out;

    // workspace layout
    short*         h1    = (short*)d_ws;                          // 67584*256 bf16 = 34.6 MB
    float*         h2    = (float*)(h1 + (size_t)67584 * 256);    //  6144*256 f32  =  6.3 MB
    short*         Wp0   = (short*)(h2 + (size_t)6144 * 256);     // 128*512 bf16 = 128 KB
    short*         Wp1   = Wp0 + (size_t)128 * 512;               // 256*512 bf16 = 256 KB
    unsigned char* mask0 = (unsigned char*)(Wp1 + (size_t)256 * 512); // 67584 B
    unsigned char* mask1 = mask0 + 67584;                         // 6144 B

    constexpr int M0 = 67584;

    // node 1: fused prep — demand marks for h1 & h2 + W packs
    k_prep<<<384, 256, 0, stream>>>(n1, n2, mask0, mask1,
                                    Ws0, Wn0, Wp0, Ws1, Wn1, Wp1);

    // node 2: layer 0 — fp32 in, bf16 out; demand-masked rows
    sage_mfma<128, 15, 32, 8, true,  false, true,  true>
        <<<M0 / 32, 256, 0, stream>>>(x,  n0, Wp0, b0, h1, mask0);

    // node 3: layer 1 — bf16 in, fp32 out; demand-masked rows
    sage_mfma<256, 10, 16, 4, true,  true,  false, true>
        <<<6144 / 16, 256, 0, stream>>>(h1, n1, Wp1, b1, h2, mask1);

    // node 4: layer 2
    sage_out<<<1024, 64, 0, stream>>>(h2, n2, Ws2, Wn2, b2, out);
}

// Round 12
// 127.773 us; speedup vs baseline: 1.4811x; 1.0021x over previous
//
#include <hip/hip_runtime.h>

using bf16x8 = __attribute__((ext_vector_type(8))) short;
using f32x4  = __attribute__((ext_vector_type(4))) float;

// ---- bf16 helpers (RNE) ----------------------------------------------------
__device__ __forceinline__ short f2bf(float x) {
    union { float f; unsigned u; } v; v.f = x;
    unsigned r = v.u + 0x7fffu + ((v.u >> 16) & 1u);
    return (short)(r >> 16);
}
__device__ __forceinline__ float bf2f(short h) {
    union { unsigned u; float f; } v; v.u = ((unsigned)(unsigned short)h) << 16;
    return v.f;
}

// ---------------------------------------------------------------------------
// Pack Wself/Wneigh (fp32, [DIN][256] each) into MFMA B-fragment order,
// bf16 hi only.  blk = ks*16+nt:  Wp[blk*512 + l*8] = frag (8 bf16).
// B-frag: lane l holds B[k = ks*32 + (l>>4)*8 + e][n = nt*16 + (l&15)]
// ---------------------------------------------------------------------------
template<int DIN>
__device__ __forceinline__ void pack_one(int blk, const float* __restrict__ Wself,
                                         const float* __restrict__ Wneigh,
                                         short* __restrict__ Wp, int l)
{
    const int ks  = blk >> 4, nt = blk & 15;
    const int col = nt * 16 + (l & 15);
    const int k0  = ks * 32 + (l >> 4) * 8;

    bf16x8 hi;
    #pragma unroll
    for (int e = 0; e < 8; ++e) {
        int k = k0 + e;
        float w = (k < DIN) ? Wself[k * 256 + col] : Wneigh[(k - DIN) * 256 + col];
        hi[e] = f2bf(w);
    }
    *reinterpret_cast<bf16x8*>(Wp + (size_t)blk * 512 + l * 8) = hi;
}

// ---------------------------------------------------------------------------
// Fused prep (single node, NO prior clear needed): demand-mark + weight-pack.
// Mark-only mask semantics: mask[i]==1 => compute row i. k_prep writes 1 to
// every NEEDED entry each call, so needed rows are always marked before the
// layer kernels read them. Unneeded entries hold whatever the buffer holds
// (0xAA poison / garbage); a spurious 1 only computes a correct-but-unused
// row (benign). Marked set is input-determined => deterministic output.
// ---------------------------------------------------------------------------
__global__ __launch_bounds__(256)
void k_prep(const int* __restrict__ neigh1, const int* __restrict__ neigh2,
            unsigned char* __restrict__ mask0, unsigned char* __restrict__ mask1,
            const float* __restrict__ Ws0, const float* __restrict__ Wn0,
            short* __restrict__ Wp0,
            const float* __restrict__ Ws1, const float* __restrict__ Wn1,
            short* __restrict__ Wp1)
{
    const int b = blockIdx.x, tid = threadIdx.x;
    if (b < 240) {
        int j = b * 256 + tid;                 // j < 61440 exactly
        mask0[neigh1[j]] = 1;
    } else if (b < 264) {
        int i = (b - 240) * 256 + tid;         // i < 6144 exactly
        mask0[i] = 1;
    } else if (b < 284) {
        int j = (b - 264) * 256 + tid;         // j < 5120 exactly
        mask1[neigh2[j]] = 1;
    } else if (b < 288) {
        int i = (b - 284) * 256 + tid;         // i < 1024 exactly
        mask1[i] = 1;
    } else {
        int unit = (b - 288) * 4 + (tid >> 6); // 384 units
        int l = tid & 63;
        if (unit < 128) pack_one<128>(unit, Ws0, Wn0, Wp0, l);
        else            pack_one<256>(unit - 128, Ws1, Wn1, Wp1, l);
    }
}

// ---------------------------------------------------------------------------
// Fused SAGE layer, bf16 MFMA (16x16x32), DOUT=256.
// Validated phase structure: nb(+need) -> barrier -> gather-mean -> barrier ->
// single k-loop GEMM -> epilogue.
//   ALO:      if true, add A-side lo-correction MFMA (al*bh) for inexact A.
//             R12: disabled everywhere — error budget shows plain-bf16 A
//             stays well under threshold (predicted absmax ~0.03 vs 0.064).
//   MASKED:   per-row demand predication via byte mask.
//   IN_BF16:  input features are bf16 (exact A-frags from memory)
//   OUT_BF16: write output as bf16
// ---------------------------------------------------------------------------
template<int DIN, int F, int RB, int NTW, bool ALO, bool MASKED, bool IN_BF16, bool OUT_BF16, bool RELU>
__global__ __launch_bounds__(256)
void sage_mfma(const void* __restrict__ h_in_v,
               const int*   __restrict__ neigh,
               const short* __restrict__ Wp,
               const float* __restrict__ bias,
               void* __restrict__ h_out_v,
               const unsigned char* __restrict__ mask)
{
    constexpr int KS    = DIN / 16;         // k-steps over Ktot = 2*DIN (32 each)
    constexpr int KSH   = DIN / 32;         // self-half k-steps
    constexpr int LROW  = DIN + 4;
    constexpr int WROWS = RB / 16;
    constexpr int WCOLS = 16 / NTW;
    static_assert(WROWS * WCOLS == 4, "4 waves");
    constexpr float invF = 1.0f / F;

    __shared__ float         An[RB][LROW];  // mean of neighbor rows (fp32)
    __shared__ int           nb[RB * F];
    __shared__ unsigned char need[RB];

    const int  tid = threadIdx.x;
    const int  w   = tid >> 6, l = tid & 63;
    const int  lr  = l & 15, lk = l >> 4;
    const long r0  = (long)blockIdx.x * RB;
    const int  wrow = (w % WROWS) * 16;
    const int  nt0  = (w / WROWS) * NTW;

    for (int p = tid; p < RB * F; p += 256)
        nb[p] = neigh[r0 * F + p];
    if constexpr (MASKED) {
        for (int p = tid; p < RB; p += 256)
            need[p] = mask[r0 + p];
    }
    __syncthreads();                        // nb (+need) ready

    if constexpr (!IN_BF16) {
        // ---- gather + mean (fp32 rows) ----
        constexpr int QD = DIN / 4;
        const float* hin = (const float*)h_in_v;
        for (int p = tid; p < RB * QD; p += 256) {
            int m = p / QD, q = p - m * QD;
            if (MASKED && need[m] != 1) continue;
            float4 a = make_float4(0.f, 0.f, 0.f, 0.f);
            #pragma unroll 5
            for (int n = 0; n < F; ++n) {
                long idx = nb[m * F + n];
                float4 v = reinterpret_cast<const float4*>(hin + idx * DIN)[q];
                a.x += v.x; a.y += v.y; a.z += v.z; a.w += v.w;
            }
            a.x *= invF; a.y *= invF; a.z *= invF; a.w *= invF;
            *reinterpret_cast<float4*>(&An[m][q * 4]) = a;
        }
    } else {
        // ---- gather + mean (bf16 rows, fp32 accumulate) ----
        constexpr int NQ = DIN / 8;
        const short* hin = (const short*)h_in_v;
        for (int p = tid; p < RB * NQ; p += 256) {
            int m = p / NQ, c = p - m * NQ;
            if (MASKED && need[m] != 1) continue;
            float a[8] = {0.f,0.f,0.f,0.f,0.f,0.f,0.f,0.f};
            #pragma unroll 5
            for (int n = 0; n < F; ++n) {
                long idx = nb[m * F + n];
                bf16x8 v = *reinterpret_cast<const bf16x8*>(hin + idx * DIN + c * 8);
                #pragma unroll
                for (int e = 0; e < 8; ++e) a[e] += bf2f(v[e]);
            }
            #pragma unroll
            for (int e = 0; e < 8; ++e) a[e] *= invF;
            *reinterpret_cast<float4*>(&An[m][c * 8])     = make_float4(a[0],a[1],a[2],a[3]);
            *reinterpret_cast<float4*>(&An[m][c * 8 + 4]) = make_float4(a[4],a[5],a[6],a[7]);
        }
    }
    __syncthreads();                        // An ready

    // ---- GEMM: single k-loop, self half from global, neigh half from LDS ----
    const float* selfrowF = (const float*)h_in_v + (r0 + wrow + lr) * DIN;
    const short* selfrowB = (const short*)h_in_v + (r0 + wrow + lr) * DIN;
    const float* neighrow = &An[wrow + lr][0];

    f32x4 acc[NTW];
    #pragma unroll
    for (int j = 0; j < NTW; ++j) acc[j] = f32x4{0.f, 0.f, 0.f, 0.f};

    for (int ks = 0; ks < KS; ++ks) {
        bf16x8 ah, al;
        bool have_lo = false;
        if (ks < KSH) {
            if constexpr (IN_BF16) {
                ah = *reinterpret_cast<const bf16x8*>(selfrowB + ks * 32 + lk * 8);
            } else {
                const int k0 = ks * 32 + lk * 8;
                float4 t0 = *reinterpret_cast<const float4*>(selfrowF + k0);
                float4 t1 = *reinterpret_cast<const float4*>(selfrowF + k0 + 4);
                float v[8] = {t0.x, t0.y, t0.z, t0.w, t1.x, t1.y, t1.z, t1.w};
                #pragma unroll
                for (int e = 0; e < 8; ++e) {
                    short h = f2bf(v[e]);
                    ah[e] = h;
                    if constexpr (ALO) al[e] = f2bf(v[e] - bf2f(h));
                }
                have_lo = ALO;
            }
        } else {
            const int k0 = (ks - KSH) * 32 + lk * 8;
            float4 t0 = *reinterpret_cast<const float4*>(neighrow + k0);
            float4 t1 = *reinterpret_cast<const float4*>(neighrow + k0 + 4);
            float v[8] = {t0.x, t0.y, t0.z, t0.w, t1.x, t1.y, t1.z, t1.w};
            #pragma unroll
            for (int e = 0; e < 8; ++e) {
                short h = f2bf(v[e]);
                ah[e] = h;
                if constexpr (ALO) al[e] = f2bf(v[e] - bf2f(h));
            }
            have_lo = ALO;
        }

        // compact Wp: 64 bf16x8 frags per (ks,nt) block
        const bf16x8* wp = reinterpret_cast<const bf16x8*>(Wp) +
                           (size_t)(ks * 16 + nt0) * 64;
        #pragma unroll
        for (int j = 0; j < NTW; ++j) {
            bf16x8 bh = wp[j * 64 + l];
            acc[j] = __builtin_amdgcn_mfma_f32_16x16x32_bf16(ah, bh, acc[j], 0, 0, 0);
            if (ALO && have_lo)
                acc[j] = __builtin_amdgcn_mfma_f32_16x16x32_bf16(al, bh, acc[j], 0, 0, 0);
        }
    }

    // ---- epilogue: bias (+relu); C/D: col=l&15, row=(l>>4)*4+r ----
    #pragma unroll
    for (int j = 0; j < NTW; ++j) {
        const int col = (nt0 + j) * 16 + lr;
        const float b = bias[col];
        #pragma unroll
        for (int r = 0; r < 4; ++r) {
            const int slot = wrow + lk * 4 + r;
            if (MASKED && need[slot] != 1) continue;
            const long row = r0 + slot;
            float val = acc[j][r] + b;
            if (RELU) val = fmaxf(val, 0.f);
            if constexpr (OUT_BF16)
                ((short*)h_out_v)[row * 256 + col] = f2bf(val);
            else
                ((float*)h_out_v)[row * 256 + col] = val;
        }
    }
}

// ---------------------------------------------------------------------------
// Final layer: M=1024, DIN=256, F=5, DOUT=47, fp32 vector math.
// 4-way accumulator split for ILP (fp32 chain is otherwise serial).
// ---------------------------------------------------------------------------
__global__ __launch_bounds__(64)
void sage_out(const float* __restrict__ h_in,
              const int*   __restrict__ neigh,
              const float* __restrict__ Wself,
              const float* __restrict__ Wneigh,
              const float* __restrict__ bias,
              float* __restrict__ out)
{
    __shared__ float hs[256], hn[256];
    __shared__ int   nb[5];
    const int r = blockIdx.x, tid = threadIdx.x;

    if (tid < 5) nb[tid] = neigh[r * 5 + tid];
    __syncthreads();

    for (int k = tid; k < 256; k += 64) {
        hs[k] = h_in[(long)r * 256 + k];
        float a = 0.f;
        #pragma unroll
        for (int n = 0; n < 5; ++n) a += h_in[(long)nb[n] * 256 + k];
        hn[k] = a * 0.2f;
    }
    __syncthreads();

    if (tid < 47) {
        float a0 = 0.f, a1 = 0.f, a2 = 0.f, a3 = 0.f;
        #pragma unroll 4
        for (int k = 0; k < 256; k += 4) {
            a0 += hs[k    ] * Wself[(k    ) * 47 + tid] + hn[k    ] * Wneigh[(k    ) * 47 + tid];
            a1 += hs[k + 1] * Wself[(k + 1) * 47 + tid] + hn[k + 1] * Wneigh[(k + 1) * 47 + tid];
            a2 += hs[k + 2] * Wself[(k + 2) * 47 + tid] + hn[k + 2] * Wneigh[(k + 2) * 47 + tid];
            a3 += hs[k + 3] * Wself[(k + 3) * 47 + tid] + hn[k + 3] * Wneigh[(k + 3) * 47 + tid];
        }
        out[r * 47 + tid] = bias[tid] + ((a0 + a1) + (a2 + a3));
    }
}

// ---------------------------------------------------------------------------
extern "C" void kernel_launch(void* const* d_in, const int* in_sizes, int n_in,
                              void* d_out, int out_size, void* d_ws, size_t ws_size,
                              hipStream_t stream)
{
    const float* x   = (const float*)d_in[0];
    const int*   n0  = (const int*)  d_in[1];
    const int*   n1  = (const int*)  d_in[2];
    const int*   n2  = (const int*)  d_in[3];
    const float* Ws0 = (const float*)d_in[4];
    const float* Wn0 = (const float*)d_in[5];
    const float* b0  = (const float*)d_in[6];
    const float* Ws1 = (const float*)d_in[7];
    const float* Wn1 = (const float*)d_in[8];
    const float* b1  = (const float*)d_in[9];
    const float* Ws2 = (const float*)d_in[10];
    const float* Wn2 = (const float*)d_in[11];
    const float* b2  = (const float*)d_in[12];
    float* out = (float*)d_out;

    // workspace layout
    short*         h1    = (short*)d_ws;                          // 67584*256 bf16 = 34.6 MB
    float*         h2    = (float*)(h1 + (size_t)67584 * 256);    //  6144*256 f32  =  6.3 MB
    short*         Wp0   = (short*)(h2 + (size_t)6144 * 256);     // 128*512 bf16 = 128 KB
    short*         Wp1   = Wp0 + (size_t)128 * 512;               // 256*512 bf16 = 256 KB
    unsigned char* mask0 = (unsigned char*)(Wp1 + (size_t)256 * 512); // 67584 B
    unsigned char* mask1 = mask0 + 67584;                         // 6144 B

    constexpr int M0 = 67584;

    // node 1: fused prep — demand marks for h1 & h2 + W packs
    k_prep<<<384, 256, 0, stream>>>(n1, n2, mask0, mask1,
                                    Ws0, Wn0, Wp0, Ws1, Wn1, Wp1);

    // node 2: layer 0 — fp32 in, bf16 out; demand-masked rows; no A-lo term
    sage_mfma<128, 15, 32, 8, false, true,  false, true,  true>
        <<<M0 / 32, 256, 0, stream>>>(x,  n0, Wp0, b0, h1, mask0);

    // node 3: layer 1 — bf16 in, fp32 out; demand-masked rows; no A-lo term
    sage_mfma<256, 10, 16, 4, false, true,  true,  false, true>
        <<<6144 / 16, 256, 0, stream>>>(h1, n1, Wp1, b1, h2, mask1);

    // node 4: layer 2
    sage_out<<<1024, 64, 0, stream>>>(h2, n2, Ws2, Wn2, b2, out);
}